// Round 1
// baseline (9385.267 us; speedup 1.0000x reference)
//
#include <hip/hip_runtime.h>
#include <math.h>

#define CH    512
#define FMPX  40
#define NP    1600          // 40*40
#define BATCH 8
#define NCLS  20
#define CONF_THR 0.001f
#define NMS_THR  0.6f

// ---------------------------------------------------------------------------
// Weight transpose: w[co][ci][ky][kx] (512x512x3x3) -> wt[tap][ci][co]
// tap = ky*3+kx. Coalesced reads (contiguous j=ci_local*9+tap runs) and
// coalesced writes (contiguous co). LDS tile padded to 73 cols: column reads
// stride 73 words -> gcd(73,32)... 73%32=9, gcd(9,32)=1 -> conflict-free.
// ---------------------------------------------------------------------------
__global__ __launch_bounds__(256)
void wtrans_kernel(const float* __restrict__ w, float* __restrict__ wt) {
    __shared__ float tile[64][73];
    const int t   = threadIdx.x;
    const int co0 = blockIdx.x * 64;   // gridDim.x = 8
    const int ci0 = blockIdx.y * 8;    // gridDim.y = 64
#pragma unroll
    for (int k = 0; k < 18; ++k) {     // 64*72 = 4608 = 18*256
        int l  = t + 256 * k;
        int co = l / 72, j = l - co * 72;
        tile[co][j] = w[(size_t)(co0 + co) * 4608 + ci0 * 9 + j];
    }
    __syncthreads();
#pragma unroll
    for (int k = 0; k < 18; ++k) {
        int l   = t + 256 * k;
        int cit = l >> 6, co = l & 63;      // cit in [0,72)
        int ci  = cit / 9, tap = cit - ci * 9;
        wt[((size_t)tap * CH + ci0 + ci) * CH + co0 + co] = tile[co][cit];
    }
}

// ---------------------------------------------------------------------------
// 3x3 conv (pad=1) + bias + leaky(0.1), as 9 shifted GEMMs.
// in/out: [B][512][1600], wt: [9][512][512] (tap,ci,co), bias: [512]
// Block 256 thr: tile 128co x 128pos, per-thread 8co x 8pos.
// tx=t&15 -> pos {tx*4..+3, 64+tx*4..+3}; ty=t>>4 -> co {ty*4..+3, 64+ty*4..+3}
// W LDS reads broadcast across tx; Il reads 2-way (free); stores float4.
// ---------------------------------------------------------------------------
__global__ __launch_bounds__(256, 2)
void conv3x3_kernel(const float* __restrict__ in, const float* __restrict__ wt,
                    const float* __restrict__ bias, float* __restrict__ out) {
    __shared__ float Wl[16][128];
    __shared__ float Il[16][128];
    const int b   = blockIdx.z;
    const int co0 = blockIdx.y * 128;
    const int p0  = blockIdx.x * 128;
    const int t   = threadIdx.x;
    const int tx  = t & 15;
    const int ty  = t >> 4;

    float acc[8][8];
#pragma unroll
    for (int i = 0; i < 8; ++i)
#pragma unroll
        for (int j = 0; j < 8; ++j) acc[i][j] = 0.f;

    for (int tap = 0; tap < 9; ++tap) {
        const int dy = tap / 3 - 1;
        const int dx = tap - (tap / 3) * 3 - 1;
        const float* wtap = wt + (size_t)tap * CH * CH;
        for (int cc = 0; cc < CH; cc += 16) {
            __syncthreads();   // protect previous chunk's LDS reads
#pragma unroll
            for (int k = 0; k < 8; ++k) {
                int l = t + 256 * k;
                int ci = l >> 7, co = l & 127;
                Wl[ci][co] = wtap[(size_t)(cc + ci) * CH + co0 + co];
            }
#pragma unroll
            for (int k = 0; k < 8; ++k) {
                int l  = t + 256 * k;
                int ci = l >> 7, pp = l & 127;
                int p  = p0 + pp;
                int y  = p / FMPX, x = p - y * FMPX;
                int yy = y + dy,  xx = x + dx;
                float v = 0.f;
                if (p < NP && (unsigned)yy < (unsigned)FMPX && (unsigned)xx < (unsigned)FMPX)
                    v = in[(size_t)(b * CH + cc + ci) * NP + yy * FMPX + xx];
                Il[ci][pp] = v;
            }
            __syncthreads();
#pragma unroll
            for (int ci = 0; ci < 16; ++ci) {
                float4 w0 = *(const float4*)&Wl[ci][ty * 4];
                float4 w1 = *(const float4*)&Wl[ci][ty * 4 + 64];
                float4 i0 = *(const float4*)&Il[ci][tx * 4];
                float4 i1 = *(const float4*)&Il[ci][tx * 4 + 64];
                float wv[8] = {w0.x, w0.y, w0.z, w0.w, w1.x, w1.y, w1.z, w1.w};
                float iv[8] = {i0.x, i0.y, i0.z, i0.w, i1.x, i1.y, i1.z, i1.w};
#pragma unroll
                for (int i = 0; i < 8; ++i)
#pragma unroll
                    for (int j = 0; j < 8; ++j)
                        acc[i][j] = fmaf(wv[i], iv[j], acc[i][j]);
            }
        }
    }
    // epilogue: bias + leaky + coalesced float4 stores
#pragma unroll
    for (int i = 0; i < 8; ++i) {
        int col = (i < 4) ? (ty * 4 + i) : (64 + ty * 4 + (i - 4));
        int co  = co0 + col;
        float bv = bias[co];
        float* op = out + (size_t)(b * CH + co) * NP + p0;
        if (p0 + tx * 4 < NP) {
            float4 v;
            v.x = acc[i][0] + bv; v.y = acc[i][1] + bv;
            v.z = acc[i][2] + bv; v.w = acc[i][3] + bv;
            v.x = v.x > 0.f ? v.x : 0.1f * v.x;
            v.y = v.y > 0.f ? v.y : 0.1f * v.y;
            v.z = v.z > 0.f ? v.z : 0.1f * v.z;
            v.w = v.w > 0.f ? v.w : 0.1f * v.w;
            *(float4*)(op + tx * 4) = v;
        }
        if (p0 + 64 + tx * 4 < NP) {
            float4 v;
            v.x = acc[i][4] + bv; v.y = acc[i][5] + bv;
            v.z = acc[i][6] + bv; v.w = acc[i][7] + bv;
            v.x = v.x > 0.f ? v.x : 0.1f * v.x;
            v.y = v.y > 0.f ? v.y : 0.1f * v.y;
            v.z = v.z > 0.f ? v.z : 0.1f * v.z;
            v.w = v.w > 0.f ? v.w : 0.1f * v.w;
            *(float4*)(op + 64 + tx * 4) = v;
        }
    }
}

// ---------------------------------------------------------------------------
// Head: 1x1 convs (obj/cls/reg) + box decode + softmax + best/argmax.
// One thread per (b,pos). Weight indices are wave-uniform -> s_loads.
// Output layout (floats): [0,51200) bboxes  [51200,64000) best
// [64000,76800) cls_inds  [76800,89600) keep (zeroed here, set by NMS)
// ---------------------------------------------------------------------------
__global__ __launch_bounds__(256)
void head_kernel(const float* __restrict__ rf, const float* __restrict__ cf,
                 const float* __restrict__ objw, const float* __restrict__ objb,
                 const float* __restrict__ clsw, const float* __restrict__ clsb,
                 const float* __restrict__ regw, const float* __restrict__ regb,
                 float* __restrict__ out) {
    int gp = blockIdx.x * 256 + threadIdx.x;
    if (gp >= BATCH * NP) return;
    int b = gp / NP, pos = gp - b * NP;
    const float* rfp = rf + (size_t)b * CH * NP + pos;
    const float* cfp = cf + (size_t)b * CH * NP + pos;
    float acc[25];
#pragma unroll
    for (int i = 0; i < 25; ++i) acc[i] = 0.f;
#pragma unroll 4
    for (int ci = 0; ci < CH; ++ci) {
        float rv = rfp[(size_t)ci * NP];
        float cv = cfp[(size_t)ci * NP];
        acc[0] = fmaf(objw[ci], rv, acc[0]);
#pragma unroll
        for (int c = 0; c < NCLS; ++c) acc[1 + c] = fmaf(clsw[c * CH + ci], cv, acc[1 + c]);
#pragma unroll
        for (int k = 0; k < 4; ++k)    acc[21 + k] = fmaf(regw[k * CH + ci], rv, acc[21 + k]);
    }
    float obj  = acc[0] + objb[0];
    float sobj = 1.f / (1.f + expf(-obj));
    float lg[NCLS];
    float m = -1e30f; int am = 0;
#pragma unroll
    for (int c = 0; c < NCLS; ++c) {
        lg[c] = acc[1 + c] + clsb[c];
        if (lg[c] > m) { m = lg[c]; am = c; }   // strict > keeps first max (jnp.argmax)
    }
    float se = 0.f;
#pragma unroll
    for (int c = 0; c < NCLS; ++c) se += expf(lg[c] - m);
    float best = sobj / se;      // sobj * exp(0)/se

    float r0 = acc[21] + regb[0], r1 = acc[22] + regb[1];
    float r2 = acc[23] + regb[2], r3 = acc[24] + regb[3];
    int gy = pos / FMPX, gx = pos - gy * FMPX;
    float cx = 1.f / (1.f + expf(-r0)) + (float)gx;
    float cy = 1.f / (1.f + expf(-r1)) + (float)gy;
    float hw = 0.5f * expf(r2);
    float hh = 0.5f * expf(r3);
    const float sc = 32.f / 1280.f;
    float x1 = fminf(fmaxf((cx - hw) * sc, 0.f), 1.f);
    float y1 = fminf(fmaxf((cy - hh) * sc, 0.f), 1.f);
    float x2 = fminf(fmaxf((cx + hw) * sc, 0.f), 1.f);
    float y2 = fminf(fmaxf((cy + hh) * sc, 0.f), 1.f);

    ((float4*)out)[gp] = make_float4(x1, y1, x2, y2);
    out[4 * BATCH * NP + gp] = best;
    out[5 * BATCH * NP + gp] = (float)am;
    out[6 * BATCH * NP + gp] = 0.f;        // keep default
}

// ---------------------------------------------------------------------------
// Greedy per-(batch,class) NMS — equivalent to the reference's rank-ordered
// suppression loop. Iterative global argmax (score desc, index asc tiebreak
// = stable argsort) then suppress IoU > 0.6 among remaining.
// ---------------------------------------------------------------------------
__global__ __launch_bounds__(256)
void nms_kernel(float* __restrict__ out) {
    const int c = blockIdx.x, b = blockIdx.y;
    __shared__ float X1[NP], Y1[NP], X2[NP], Y2[NP], AR[NP], S[NP];
    __shared__ float wr_s[4];
    __shared__ int   wr_i[4];
    const int t = threadIdx.x;

    for (int j = t; j < NP; j += 256) {
        int gp = b * NP + j;
        float4 bx = ((const float4*)out)[gp];
        float best = out[4 * BATCH * NP + gp];
        int   ci   = (int)out[5 * BATCH * NP + gp];
        X1[j] = bx.x; Y1[j] = bx.y; X2[j] = bx.z; Y2[j] = bx.w;
        AR[j] = (bx.z - bx.x) * (bx.w - bx.y);
        S[j]  = (ci == c && best >= CONF_THR) ? best : -1.f;
    }
    __syncthreads();

    while (true) {
        // local argmax over this thread's strided entries (ascending j ->
        // strict > keeps the smallest index among equal scores)
        float bs = -1.f; int bi = -1;
        for (int j = t; j < NP; j += 256) {
            float s = S[j];
            if (s > bs) { bs = s; bi = j; }
        }
        // wave-level reduce (64 lanes)
#pragma unroll
        for (int off = 32; off > 0; off >>= 1) {
            float s2 = __shfl_down(bs, off);
            int   i2 = __shfl_down(bi, off);
            if (s2 > bs || (s2 == bs && i2 != -1 && (bi == -1 || i2 < bi))) { bs = s2; bi = i2; }
        }
        if ((t & 63) == 0) { wr_s[t >> 6] = bs; wr_i[t >> 6] = bi; }
        __syncthreads();
        float ks = wr_s[0]; int k = wr_i[0];
#pragma unroll
        for (int w = 1; w < 4; ++w) {
            float s2 = wr_s[w]; int i2 = wr_i[w];
            if (s2 > ks || (s2 == ks && i2 != -1 && (k == -1 || i2 < k))) { ks = s2; k = i2; }
        }
        if (k < 0) break;
        // suppression (each thread owns its strided j's; no write races)
        for (int j = t; j < NP; j += 256) {
            if (j == k) {
                S[j] = -1.f;
                out[6 * BATCH * NP + b * NP + j] = 1.f;   // kept
                continue;
            }
            float s = S[j];
            if (s < 0.f) continue;
            float xx1 = fmaxf(X1[k], X1[j]);
            float yy1 = fmaxf(Y1[k], Y1[j]);
            float xx2 = fminf(X2[k], X2[j]);
            float yy2 = fminf(Y2[k], Y2[j]);
            float w = fmaxf(1e-28f, xx2 - xx1);
            float h = fmaxf(1e-28f, yy2 - yy1);
            float inter = w * h;
            float iou = inter / (AR[k] + AR[j] - inter + 1e-14f);
            if (iou > NMS_THR) S[j] = -1.f;
        }
        __syncthreads();   // S updates + wr reuse ordering for next round
    }
}

// ---------------------------------------------------------------------------
extern "C" void kernel_launch(void* const* d_in, const int* in_sizes, int n_in,
                              void* d_out, int out_size, void* d_ws, size_t ws_size,
                              hipStream_t stream) {
    const float* x      = (const float*)d_in[0];
    const float* cls_w  = (const float*)d_in[1];
    const float* cls_b  = (const float*)d_in[2];
    const float* reg_w  = (const float*)d_in[3];
    const float* reg_b  = (const float*)d_in[4];
    const float* obj_w  = (const float*)d_in[5];
    const float* obj_b  = (const float*)d_in[6];
    const float* clsp_w = (const float*)d_in[7];
    const float* clsp_b = (const float*)d_in[8];
    const float* regp_w = (const float*)d_in[9];
    const float* regp_b = (const float*)d_in[10];
    float* out = (float*)d_out;

    const size_t FEAT = (size_t)BATCH * CH * NP;   // 6,553,600 floats
    const size_t LW   = (size_t)CH * CH * 9;       // per-layer weight elems
    float* f0 = (float*)d_ws;                      // ws need: 3*FEAT + LW floats
    float* f1 = f0 + FEAT;                         //  = 88,080,384 bytes
    float* f2 = f1 + FEAT;
    float* wt = f2 + FEAT;

    dim3 tgrid(8, 64), tblk(256);
    dim3 cgrid(13, 4, 8), cblk(256);

    // cls chain: x -> f0 -> f1  (cf = f1)
    wtrans_kernel<<<tgrid, tblk, 0, stream>>>(cls_w, wt);
    conv3x3_kernel<<<cgrid, cblk, 0, stream>>>(x,  wt, cls_b,          f0);
    wtrans_kernel<<<tgrid, tblk, 0, stream>>>(cls_w + LW, wt);
    conv3x3_kernel<<<cgrid, cblk, 0, stream>>>(f0, wt, cls_b + CH,     f1);
    // reg chain: x -> f0 -> f2 -> f0 -> f2  (rf = f2)
    wtrans_kernel<<<tgrid, tblk, 0, stream>>>(reg_w, wt);
    conv3x3_kernel<<<cgrid, cblk, 0, stream>>>(x,  wt, reg_b,          f0);
    wtrans_kernel<<<tgrid, tblk, 0, stream>>>(reg_w + LW, wt);
    conv3x3_kernel<<<cgrid, cblk, 0, stream>>>(f0, wt, reg_b + CH,     f2);
    wtrans_kernel<<<tgrid, tblk, 0, stream>>>(reg_w + 2 * LW, wt);
    conv3x3_kernel<<<cgrid, cblk, 0, stream>>>(f2, wt, reg_b + 2 * CH, f0);
    wtrans_kernel<<<tgrid, tblk, 0, stream>>>(reg_w + 3 * LW, wt);
    conv3x3_kernel<<<cgrid, cblk, 0, stream>>>(f0, wt, reg_b + 3 * CH, f2);

    head_kernel<<<dim3(50), 256, 0, stream>>>(f2, f1, obj_w, obj_b,
                                              clsp_w, clsp_b, regp_w, regp_b, out);
    nms_kernel<<<dim3(NCLS, BATCH), 256, 0, stream>>>(out);
}

// Round 2
// 6817.010 us; speedup vs baseline: 1.3767x; 1.3767x over previous
//
#include <hip/hip_runtime.h>
#include <math.h>

#define CH    512
#define FMPX  40
#define NP    1600          // 40*40
#define BATCH 8
#define NCLS  20
#define CONF_THR 0.001f
#define NMS_THR  0.6f

// ---------------------------------------------------------------------------
// Weight transpose: w[co][ci][ky][kx] (512x512x3x3) -> wt[tap][ci][co]
// ---------------------------------------------------------------------------
__global__ __launch_bounds__(256)
void wtrans_kernel(const float* __restrict__ w, float* __restrict__ wt) {
    __shared__ float tile[64][73];
    const int t   = threadIdx.x;
    const int co0 = blockIdx.x * 64;   // gridDim.x = 8
    const int ci0 = blockIdx.y * 8;    // gridDim.y = 64
#pragma unroll
    for (int k = 0; k < 18; ++k) {     // 64*72 = 4608 = 18*256
        int l  = t + 256 * k;
        int co = l / 72, j = l - co * 72;
        tile[co][j] = w[(size_t)(co0 + co) * 4608 + ci0 * 9 + j];
    }
    __syncthreads();
#pragma unroll
    for (int k = 0; k < 18; ++k) {
        int l   = t + 256 * k;
        int cit = l >> 6, co = l & 63;      // cit in [0,72)
        int ci  = cit / 9, tap = cit - ci * 9;
        wt[((size_t)tap * CH + ci0 + ci) * CH + co0 + co] = tile[co][cit];
    }
}

// ---------------------------------------------------------------------------
// 3x3 conv (pad=1) + bias + leaky(0.1), as 9 shifted GEMMs. (unchanged R1)
// ---------------------------------------------------------------------------
__global__ __launch_bounds__(256, 2)
void conv3x3_kernel(const float* __restrict__ in, const float* __restrict__ wt,
                    const float* __restrict__ bias, float* __restrict__ out) {
    __shared__ float Wl[16][128];
    __shared__ float Il[16][128];
    const int b   = blockIdx.z;
    const int co0 = blockIdx.y * 128;
    const int p0  = blockIdx.x * 128;
    const int t   = threadIdx.x;
    const int tx  = t & 15;
    const int ty  = t >> 4;

    float acc[8][8];
#pragma unroll
    for (int i = 0; i < 8; ++i)
#pragma unroll
        for (int j = 0; j < 8; ++j) acc[i][j] = 0.f;

    for (int tap = 0; tap < 9; ++tap) {
        const int dy = tap / 3 - 1;
        const int dx = tap - (tap / 3) * 3 - 1;
        const float* wtap = wt + (size_t)tap * CH * CH;
        for (int cc = 0; cc < CH; cc += 16) {
            __syncthreads();
#pragma unroll
            for (int k = 0; k < 8; ++k) {
                int l = t + 256 * k;
                int ci = l >> 7, co = l & 127;
                Wl[ci][co] = wtap[(size_t)(cc + ci) * CH + co0 + co];
            }
#pragma unroll
            for (int k = 0; k < 8; ++k) {
                int l  = t + 256 * k;
                int ci = l >> 7, pp = l & 127;
                int p  = p0 + pp;
                int y  = p / FMPX, x = p - y * FMPX;
                int yy = y + dy,  xx = x + dx;
                float v = 0.f;
                if (p < NP && (unsigned)yy < (unsigned)FMPX && (unsigned)xx < (unsigned)FMPX)
                    v = in[(size_t)(b * CH + cc + ci) * NP + yy * FMPX + xx];
                Il[ci][pp] = v;
            }
            __syncthreads();
#pragma unroll
            for (int ci = 0; ci < 16; ++ci) {
                float4 w0 = *(const float4*)&Wl[ci][ty * 4];
                float4 w1 = *(const float4*)&Wl[ci][ty * 4 + 64];
                float4 i0 = *(const float4*)&Il[ci][tx * 4];
                float4 i1 = *(const float4*)&Il[ci][tx * 4 + 64];
                float wv[8] = {w0.x, w0.y, w0.z, w0.w, w1.x, w1.y, w1.z, w1.w};
                float iv[8] = {i0.x, i0.y, i0.z, i0.w, i1.x, i1.y, i1.z, i1.w};
#pragma unroll
                for (int i = 0; i < 8; ++i)
#pragma unroll
                    for (int j = 0; j < 8; ++j)
                        acc[i][j] = fmaf(wv[i], iv[j], acc[i][j]);
            }
        }
    }
#pragma unroll
    for (int i = 0; i < 8; ++i) {
        int col = (i < 4) ? (ty * 4 + i) : (64 + ty * 4 + (i - 4));
        int co  = co0 + col;
        float bv = bias[co];
        float* op = out + (size_t)(b * CH + co) * NP + p0;
        if (p0 + tx * 4 < NP) {
            float4 v;
            v.x = acc[i][0] + bv; v.y = acc[i][1] + bv;
            v.z = acc[i][2] + bv; v.w = acc[i][3] + bv;
            v.x = v.x > 0.f ? v.x : 0.1f * v.x;
            v.y = v.y > 0.f ? v.y : 0.1f * v.y;
            v.z = v.z > 0.f ? v.z : 0.1f * v.z;
            v.w = v.w > 0.f ? v.w : 0.1f * v.w;
            *(float4*)(op + tx * 4) = v;
        }
        if (p0 + 64 + tx * 4 < NP) {
            float4 v;
            v.x = acc[i][4] + bv; v.y = acc[i][5] + bv;
            v.z = acc[i][6] + bv; v.w = acc[i][7] + bv;
            v.x = v.x > 0.f ? v.x : 0.1f * v.x;
            v.y = v.y > 0.f ? v.y : 0.1f * v.y;
            v.z = v.z > 0.f ? v.z : 0.1f * v.z;
            v.w = v.w > 0.f ? v.w : 0.1f * v.w;
            *(float4*)(op + 64 + tx * 4) = v;
        }
    }
}

// ---------------------------------------------------------------------------
// Head: 1x1 convs + box decode + softmax + best/argmax. (unchanged R1)
// Output layout (floats): [0,51200) bboxes  [51200,64000) best
// [64000,76800) cls_inds  [76800,89600) keep (zeroed here, set by NMS)
// ---------------------------------------------------------------------------
__global__ __launch_bounds__(256)
void head_kernel(const float* __restrict__ rf, const float* __restrict__ cf,
                 const float* __restrict__ objw, const float* __restrict__ objb,
                 const float* __restrict__ clsw, const float* __restrict__ clsb,
                 const float* __restrict__ regw, const float* __restrict__ regb,
                 float* __restrict__ out) {
    int gp = blockIdx.x * 256 + threadIdx.x;
    if (gp >= BATCH * NP) return;
    int b = gp / NP, pos = gp - b * NP;
    const float* rfp = rf + (size_t)b * CH * NP + pos;
    const float* cfp = cf + (size_t)b * CH * NP + pos;
    float acc[25];
#pragma unroll
    for (int i = 0; i < 25; ++i) acc[i] = 0.f;
#pragma unroll 4
    for (int ci = 0; ci < CH; ++ci) {
        float rv = rfp[(size_t)ci * NP];
        float cv = cfp[(size_t)ci * NP];
        acc[0] = fmaf(objw[ci], rv, acc[0]);
#pragma unroll
        for (int c = 0; c < NCLS; ++c) acc[1 + c] = fmaf(clsw[c * CH + ci], cv, acc[1 + c]);
#pragma unroll
        for (int k = 0; k < 4; ++k)    acc[21 + k] = fmaf(regw[k * CH + ci], rv, acc[21 + k]);
    }
    float obj  = acc[0] + objb[0];
    float sobj = 1.f / (1.f + expf(-obj));
    float lg[NCLS];
    float m = -1e30f; int am = 0;
#pragma unroll
    for (int c = 0; c < NCLS; ++c) {
        lg[c] = acc[1 + c] + clsb[c];
        if (lg[c] > m) { m = lg[c]; am = c; }
    }
    float se = 0.f;
#pragma unroll
    for (int c = 0; c < NCLS; ++c) se += expf(lg[c] - m);
    float best = sobj / se;

    float r0 = acc[21] + regb[0], r1 = acc[22] + regb[1];
    float r2 = acc[23] + regb[2], r3 = acc[24] + regb[3];
    int gy = pos / FMPX, gx = pos - gy * FMPX;
    float cx = 1.f / (1.f + expf(-r0)) + (float)gx;
    float cy = 1.f / (1.f + expf(-r1)) + (float)gy;
    float hw = 0.5f * expf(r2);
    float hh = 0.5f * expf(r3);
    const float sc = 32.f / 1280.f;
    float x1 = fminf(fmaxf((cx - hw) * sc, 0.f), 1.f);
    float y1 = fminf(fmaxf((cy - hh) * sc, 0.f), 1.f);
    float x2 = fminf(fmaxf((cx + hw) * sc, 0.f), 1.f);
    float y2 = fminf(fmaxf((cy + hh) * sc, 0.f), 1.f);

    ((float4*)out)[gp] = make_float4(x1, y1, x2, y2);
    out[4 * BATCH * NP + gp] = best;
    out[5 * BATCH * NP + gp] = (float)am;
    out[6 * BATCH * NP + gp] = 0.f;
}

// ---------------------------------------------------------------------------
// Sort-based greedy NMS, one block per (b,c).
// 1) keys = (score_bits<<32)|(0xFFFFFFFF-idx), sort desc (via ~key asc bitonic)
//    == stable argsort(-score): score desc, index asc on ties.
// 2) chunks of 64 sorted boxes: test vs kept list (4 waves split kept list,
//    kept box = LDS broadcast), then wave0 resolves intra-chunk suppression
//    via per-lane 64-bit suppressor masks + ballot loop.
// Greedy semantics identical to reference (suppressed boxes never suppress).
// ---------------------------------------------------------------------------
__global__ __launch_bounds__(256)
void nms_kernel(float* __restrict__ out) {
    const int c = blockIdx.x, b = blockIdx.y;
    const int t = threadIdx.x;
    const int w = t >> 6, l = t & 63;

    __shared__ unsigned long long skey[2048];
    __shared__ float4 CBox[NP];      // candidate boxes by original index
    __shared__ float4 KBox[NP];      // kept boxes in keep order
    __shared__ float4 CB64[64];      // current chunk's boxes
    __shared__ unsigned long long wmask[4];
    __shared__ int Kcnt;

    // ---- load + key build ----
    for (int j = t; j < NP; j += 256) {
        int gp = b * NP + j;
        float4 bx = ((const float4*)out)[gp];
        float best = out[4 * BATCH * NP + gp];
        int   ci   = (int)out[5 * BATCH * NP + gp];
        CBox[j] = bx;
        bool alive = (ci == c) && (best >= CONF_THR);
        unsigned long long key = alive
            ? ~(((unsigned long long)__float_as_uint(best) << 32)
                | (unsigned long long)(0xFFFFFFFFu - (unsigned)j))
            : ~0ull;
        skey[j] = key;
    }
    for (int j = NP + t; j < 2048; j += 256) skey[j] = ~0ull;
    if (t == 0) Kcnt = 0;

    // ---- bitonic sort ascending on ~K (= descending on K) ----
    for (unsigned k = 2; k <= 2048; k <<= 1) {
        for (unsigned j = k >> 1; j > 0; j >>= 1) {
            __syncthreads();
            for (unsigned i = t; i < 2048; i += 256) {
                unsigned p = i ^ j;
                if (p > i) {
                    bool up = ((i & k) == 0);
                    unsigned long long a = skey[i], bq = skey[p];
                    if ((a > bq) == up) { skey[i] = bq; skey[p] = a; }
                }
            }
        }
    }
    __syncthreads();

    // ---- greedy over sorted chunks of 64 ----
    float* keepout = out + 6 * BATCH * NP + b * NP;
    for (int base = 0; base < NP; base += 64) {
        unsigned long long ik = skey[base + l];
        bool valid = (ik != ~0ull);
        unsigned long long vm = __ballot(valid);   // same value in every wave
        if (vm == 0) break;                        // sorted: nothing follows

        unsigned idx = 0;
        float4 bx = make_float4(0.f, 0.f, 0.f, 0.f);
        float ar = 0.f;
        if (valid) {
            unsigned long long K = ~ik;
            idx = 0xFFFFFFFFu - (unsigned)(K & 0xFFFFFFFFull);
            bx  = CBox[idx];
            ar  = (bx.z - bx.x) * (bx.w - bx.y);
        }
        if (w == 0) CB64[l] = bx;   // wave0 stages chunk boxes for resolution
        int prevK = Kcnt;

        // test vs previously-kept (kept list strided across 4 waves)
        bool sup = false;
        for (int k = w; k < prevK; k += 4) {
            float4 kb = KBox[k];                       // LDS broadcast
            float kar = (kb.z - kb.x) * (kb.w - kb.y);
            float xx1 = fmaxf(kb.x, bx.x);
            float yy1 = fmaxf(kb.y, bx.y);
            float xx2 = fminf(kb.z, bx.z);
            float yy2 = fminf(kb.w, bx.w);
            float ww = fmaxf(1e-28f, xx2 - xx1);
            float hh = fmaxf(1e-28f, yy2 - yy1);
            float inter = ww * hh;
            float iou = inter / (kar + ar - inter + 1e-14f);
            sup |= (iou > NMS_THR);
        }
        wmask[w] = __ballot(valid && !sup);
        __syncthreads();

        if (w == 0) {
            unsigned long long alive =
                wmask[0] & wmask[1] & wmask[2] & wmask[3];
            // per-lane suppressor mask: bits s<l with IoU(l,s)>thr
            unsigned long long smask = 0;
            for (int s = 0; s < 64; ++s) {
                float4 ob = CB64[s];                   // broadcast
                float oar = (ob.z - ob.x) * (ob.w - ob.y);
                float xx1 = fmaxf(ob.x, bx.x);
                float yy1 = fmaxf(ob.y, bx.y);
                float xx2 = fminf(ob.z, bx.z);
                float yy2 = fminf(ob.w, bx.w);
                float ww = fmaxf(1e-28f, xx2 - xx1);
                float hh = fmaxf(1e-28f, yy2 - yy1);
                float inter = ww * hh;
                float iou = inter / (oar + ar - inter + 1e-14f);
                if (s < l && iou > NMS_THR) smask |= (1ull << s);
            }
            unsigned long long kept = 0;
            while (alive) {
                int s = __builtin_ctzll(alive);        // best remaining score
                kept |= (1ull << s);
                alive &= ~(1ull << s);
                unsigned long long dead = __ballot((smask >> s) & 1ull);
                alive &= ~dead;                        // only alive bits matter
            }
            if ((kept >> l) & 1ull) {
                int pos = prevK + __builtin_popcountll(kept & ((1ull << l) - 1ull));
                KBox[pos] = bx;
                keepout[idx] = 1.0f;
            }
            if (l == 0) Kcnt = prevK + __builtin_popcountll(kept);
        }
        __syncthreads();
    }
}

// ---------------------------------------------------------------------------
extern "C" void kernel_launch(void* const* d_in, const int* in_sizes, int n_in,
                              void* d_out, int out_size, void* d_ws, size_t ws_size,
                              hipStream_t stream) {
    const float* x      = (const float*)d_in[0];
    const float* cls_w  = (const float*)d_in[1];
    const float* cls_b  = (const float*)d_in[2];
    const float* reg_w  = (const float*)d_in[3];
    const float* reg_b  = (const float*)d_in[4];
    const float* obj_w  = (const float*)d_in[5];
    const float* obj_b  = (const float*)d_in[6];
    const float* clsp_w = (const float*)d_in[7];
    const float* clsp_b = (const float*)d_in[8];
    const float* regp_w = (const float*)d_in[9];
    const float* regp_b = (const float*)d_in[10];
    float* out = (float*)d_out;

    const size_t FEAT = (size_t)BATCH * CH * NP;
    const size_t LW   = (size_t)CH * CH * 9;
    float* f0 = (float*)d_ws;
    float* f1 = f0 + FEAT;
    float* f2 = f1 + FEAT;
    float* wt = f2 + FEAT;

    dim3 tgrid(8, 64), tblk(256);
    dim3 cgrid(13, 4, 8), cblk(256);

    wtrans_kernel<<<tgrid, tblk, 0, stream>>>(cls_w, wt);
    conv3x3_kernel<<<cgrid, cblk, 0, stream>>>(x,  wt, cls_b,          f0);
    wtrans_kernel<<<tgrid, tblk, 0, stream>>>(cls_w + LW, wt);
    conv3x3_kernel<<<cgrid, cblk, 0, stream>>>(f0, wt, cls_b + CH,     f1);
    wtrans_kernel<<<tgrid, tblk, 0, stream>>>(reg_w, wt);
    conv3x3_kernel<<<cgrid, cblk, 0, stream>>>(x,  wt, reg_b,          f0);
    wtrans_kernel<<<tgrid, tblk, 0, stream>>>(reg_w + LW, wt);
    conv3x3_kernel<<<cgrid, cblk, 0, stream>>>(f0, wt, reg_b + CH,     f2);
    wtrans_kernel<<<tgrid, tblk, 0, stream>>>(reg_w + 2 * LW, wt);
    conv3x3_kernel<<<cgrid, cblk, 0, stream>>>(f2, wt, reg_b + 2 * CH, f0);
    wtrans_kernel<<<tgrid, tblk, 0, stream>>>(reg_w + 3 * LW, wt);
    conv3x3_kernel<<<cgrid, cblk, 0, stream>>>(f0, wt, reg_b + 3 * CH, f2);

    head_kernel<<<dim3(50), 256, 0, stream>>>(f2, f1, obj_w, obj_b,
                                              clsp_w, clsp_b, regp_w, regp_b, out);
    nms_kernel<<<dim3(NCLS, BATCH), 256, 0, stream>>>(out);
}

// Round 3
// 4039.845 us; speedup vs baseline: 2.3232x; 1.6874x over previous
//
#include <hip/hip_runtime.h>
#include <math.h>

#define CH    512
#define FMPX  40
#define PW    42            // padded row width
#define PADN  1764          // 42*42
#define NP    1600          // 40*40
#define BATCH 8
#define NCLS  20
#define CONF_THR 0.001f
#define NMS_THR  0.6f

typedef _Float16 v8h __attribute__((ext_vector_type(8)));
typedef float    v4f __attribute__((ext_vector_type(4)));

// ws layout (in _Float16 units). 6 feature planes contiguous, then weights.
#define FPLANE  ((size_t)BATCH * PADN * CH)          // 7,225,344 halves
#define WSZ     ((size_t)9 * CH * CH)                // 2,359,296 halves
// total: 6*FPLANE + 2*WSZ = 48,070,656 halves = 96.1 MB

__device__ __forceinline__ int padidx(int p) { return p + 2 * (p / FMPX) + PW + 1; }

// ---------------------------------------------------------------------------
// Zero the padded borders of all 6 feature planes (ws re-poisoned each call).
// 6 planes * 8 b * 164 border cells * 64 uint4 = 503808 stores.
// ---------------------------------------------------------------------------
__global__ __launch_bounds__(256)
void border_zero(uint4* __restrict__ ws) {
    int idx = blockIdx.x * 256 + threadIdx.x;           // grid 1968 blocks exact
    int u    = idx & 63;
    int cell = (idx >> 6) % 164;
    int b    = (idx / (64 * 164)) & 7;
    int pl   = idx / (64 * 164 * 8);
    int pi;
    if (cell < 42)      pi = cell;
    else if (cell < 84) pi = 41 * PW + (cell - 42);
    else { int r = cell - 84; pi = (1 + (r >> 1)) * PW + ((r & 1) ? 41 : 0); }
    size_t hoff = (size_t)pl * FPLANE + (size_t)b * (PADN * CH) + (size_t)pi * CH;
    ws[(hoff >> 3) + u] = make_uint4(0u, 0u, 0u, 0u);
}

// ---------------------------------------------------------------------------
// x [b][512][1600] fp32 -> padded pos-major fp16 hi/lo planes [b][1764][512].
// lo scaled by 2048 (fits fp16 normals; combined precision ~2^-22).
// ---------------------------------------------------------------------------
__global__ __launch_bounds__(256)
void xprep_kernel(const float* __restrict__ x, _Float16* __restrict__ Xh,
                  _Float16* __restrict__ Xl) {
    __shared__ float T[64][65];
    const int t = threadIdx.x;
    const int p0  = blockIdx.x * 64;   // 25
    const int ci0 = blockIdx.y * 64;   // 8
    const int b   = blockIdx.z;        // 8
#pragma unroll
    for (int it = 0; it < 16; ++it) {
        int row = (t >> 6) + 4 * it;   // ci local
        int col = t & 63;              // pos local
        T[col][row] = x[((size_t)b * CH + ci0 + row) * NP + p0 + col];
    }
    __syncthreads();
#pragma unroll
    for (int it = 0; it < 16; ++it) {
        int posl = (t >> 6) + 4 * it;
        int ci   = t & 63;
        float v = T[posl][ci];
        _Float16 h = (_Float16)v;
        _Float16 l = (_Float16)((v - (float)h) * 2048.0f);
        size_t o = (size_t)b * (PADN * CH) + (size_t)padidx(p0 + posl) * CH + ci0 + ci;
        Xh[o] = h; Xl[o] = l;
    }
}

// ---------------------------------------------------------------------------
// w [co][ci][3][3] fp32 -> Wh/Wl [tap][co][ci] fp16.
// Wh = fp16(16*w)  (x16 keeps tiny weights out of subnormal-flush range)
// Wl = fp16(32768*(w - Wh/16))
// ---------------------------------------------------------------------------
__global__ __launch_bounds__(256)
void wtrans_kernel(const float* __restrict__ w, _Float16* __restrict__ Wh,
                   _Float16* __restrict__ Wl) {
    __shared__ float tile[32][289];
    const int t = threadIdx.x;
    const int co0 = blockIdx.x * 32;   // 16
    const int ci0 = blockIdx.y * 32;   // 16
#pragma unroll
    for (int g = 0; g < 36; ++g) {     // 32*288 = 9216
        int l = t + 256 * g;
        int co = l / 288, j = l - co * 288;
        tile[co][j] = w[(size_t)(co0 + co) * 4608 + ci0 * 9 + j];
    }
    __syncthreads();
#pragma unroll
    for (int tap = 0; tap < 9; ++tap) {
#pragma unroll
        for (int cg = 0; cg < 4; ++cg) {
            int co = cg * 8 + (t >> 5);
            int ci = t & 31;
            float v = tile[co][ci * 9 + tap];
            _Float16 h = (_Float16)(16.0f * v);
            _Float16 l = (_Float16)((v - (float)h * 0.0625f) * 32768.0f);
            size_t o = ((size_t)tap * CH + co0 + co) * CH + ci0 + ci;
            Wh[o] = h; Wl[o] = l;
        }
    }
}

// ---------------------------------------------------------------------------
// 3x3 conv via MFMA, split-fp16, direct-from-global fragments (no LDS).
// GEMM: C[pos][co] += sum_{tap,ci} I_shift[pos][ci] * W[tap][co][ci]
// Block 256 thr = 4 waves; block tile M=64 pos x N=256 co; wave 64x64 (4x4
// of 16x16x32). acc1 = hh (x16), acc2 = cross terms (x32768).
// v = acc1/16 + acc2/32768 + bias -> leaky -> split-store hi/lo.
// ---------------------------------------------------------------------------
__global__ __launch_bounds__(256, 2)
void conv_mfma(const _Float16* __restrict__ Ih, const _Float16* __restrict__ Il,
               const _Float16* __restrict__ Wh, const _Float16* __restrict__ Wl,
               const float* __restrict__ bias,
               _Float16* __restrict__ Oh, _Float16* __restrict__ Ol) {
    const int t = threadIdx.x;
    const int wv = t >> 6, l = t & 63;
    const int quad = l >> 4, col = l & 15;
    const int bx = blockIdx.x;               // 0..199
    const int b  = bx / 25;
    const int p0 = (bx - b * 25) * 64;
    const int co0 = blockIdx.y * 256 + wv * 64;
    const size_t boff = (size_t)b * (PADN * CH);

    int aoff[4], woff[4];
#pragma unroll
    for (int i = 0; i < 4; ++i) {
        int p = p0 + i * 16 + col;
        aoff[i] = padidx(p) * CH + quad * 8;
    }
#pragma unroll
    for (int j = 0; j < 4; ++j)
        woff[j] = (co0 + j * 16 + col) * CH + quad * 8;

    v4f acc1[4][4], acc2[4][4];
#pragma unroll
    for (int i = 0; i < 4; ++i)
#pragma unroll
        for (int j = 0; j < 4; ++j) {
            acc1[i][j] = (v4f){0.f, 0.f, 0.f, 0.f};
            acc2[i][j] = (v4f){0.f, 0.f, 0.f, 0.f};
        }

    for (int tap = 0; tap < 9; ++tap) {
        const int dy = tap / 3 - 1, dx = tap - (tap / 3) * 3 - 1;
        const int tsh = (dy * PW + dx) * CH;
        const _Float16* pah = Ih + boff + tsh;
        const _Float16* pal = Il + boff + tsh;
        const _Float16* pwh = Wh + (size_t)tap * (CH * CH);
        const _Float16* pwl = Wl + (size_t)tap * (CH * CH);
#pragma unroll 4
        for (int kc = 0; kc < 16; ++kc) {
            const int c0 = kc * 32;
            v8h ah[4], al[4];
#pragma unroll
            for (int i = 0; i < 4; ++i) {
                ah[i] = *(const v8h*)(pah + aoff[i] + c0);
                al[i] = *(const v8h*)(pal + aoff[i] + c0);
            }
#pragma unroll
            for (int j = 0; j < 4; ++j) {
                v8h bh = *(const v8h*)(pwh + woff[j] + c0);
                v8h bl = *(const v8h*)(pwl + woff[j] + c0);
#pragma unroll
                for (int i = 0; i < 4; ++i)
                    acc1[i][j] = __builtin_amdgcn_mfma_f32_16x16x32_f16(ah[i], bh, acc1[i][j], 0, 0, 0);
#pragma unroll
                for (int i = 0; i < 4; ++i)
                    acc2[i][j] = __builtin_amdgcn_mfma_f32_16x16x32_f16(ah[i], bl, acc2[i][j], 0, 0, 0);
#pragma unroll
                for (int i = 0; i < 4; ++i)
                    acc2[i][j] = __builtin_amdgcn_mfma_f32_16x16x32_f16(al[i], bh, acc2[i][j], 0, 0, 0);
            }
        }
    }

    // epilogue: combine, bias, leaky, split-store
#pragma unroll
    for (int i = 0; i < 4; ++i) {
#pragma unroll
        for (int j = 0; j < 4; ++j) {
            int n = co0 + j * 16 + col;
            float bv = bias[n];
#pragma unroll
            for (int r = 0; r < 4; ++r) {
                int p = p0 + i * 16 + quad * 4 + r;
                float v = acc1[i][j][r] * 0.0625f + acc2[i][j][r] * (1.0f / 32768.0f) + bv;
                v = v > 0.f ? v : 0.1f * v;
                _Float16 h = (_Float16)v;
                _Float16 lo = (_Float16)((v - (float)h) * 2048.0f);
                size_t o = boff + (size_t)padidx(p) * CH + n;
                Oh[o] = h; Ol[o] = lo;
            }
        }
    }
}

// ---------------------------------------------------------------------------
// Head: 1x1 convs + decode. One wave per (b,pos); lanes split ci (64x8=512).
// Output layout (floats): [0,51200) bboxes  [51200,64000) best
// [64000,76800) cls_inds  [76800,89600) keep (zeroed here, set by NMS)
// ---------------------------------------------------------------------------
__global__ __launch_bounds__(256)
void head_kernel(const _Float16* __restrict__ Rh, const _Float16* __restrict__ Rl,
                 const _Float16* __restrict__ Ch, const _Float16* __restrict__ Cl,
                 const float* __restrict__ objw, const float* __restrict__ objb,
                 const float* __restrict__ clsw, const float* __restrict__ clsb,
                 const float* __restrict__ regw, const float* __restrict__ regb,
                 float* __restrict__ out) {
    const int wid = (blockIdx.x * 256 + threadIdx.x) >> 6;  // 0..12799
    const int l = threadIdx.x & 63;
    const int b = wid / NP, p = wid - b * NP;
    const size_t base = (size_t)b * (PADN * CH) + (size_t)padidx(p) * CH + l * 8;

    v8h rh = *(const v8h*)(Rh + base), rl = *(const v8h*)(Rl + base);
    v8h ch = *(const v8h*)(Ch + base), cl = *(const v8h*)(Cl + base);
    float rv[8], cv[8];
#pragma unroll
    for (int k = 0; k < 8; ++k) {
        rv[k] = (float)rh[k] + (float)rl[k] * (1.0f / 2048.0f);
        cv[k] = (float)ch[k] + (float)cl[k] * (1.0f / 2048.0f);
    }
    float s[25];
#pragma unroll
    for (int o = 0; o < 25; ++o) s[o] = 0.f;
#pragma unroll
    for (int k = 0; k < 8; ++k) s[0] = fmaf(objw[l * 8 + k], rv[k], s[0]);
#pragma unroll
    for (int c = 0; c < NCLS; ++c)
#pragma unroll
        for (int k = 0; k < 8; ++k) s[1 + c] = fmaf(clsw[c * CH + l * 8 + k], cv[k], s[1 + c]);
#pragma unroll
    for (int q = 0; q < 4; ++q)
#pragma unroll
        for (int k = 0; k < 8; ++k) s[21 + q] = fmaf(regw[q * CH + l * 8 + k], rv[k], s[21 + q]);
#pragma unroll
    for (int o = 0; o < 25; ++o) {
#pragma unroll
        for (int off = 32; off > 0; off >>= 1) s[o] += __shfl_xor(s[o], off);
    }
    if (l == 0) {
        int gp = b * NP + p;
        float obj  = s[0] + objb[0];
        float sobj = 1.f / (1.f + expf(-obj));
        float lg[NCLS];
        float m = -1e30f; int am = 0;
#pragma unroll
        for (int c = 0; c < NCLS; ++c) {
            lg[c] = s[1 + c] + clsb[c];
            if (lg[c] > m) { m = lg[c]; am = c; }   // strict > = first max
        }
        float se = 0.f;
#pragma unroll
        for (int c = 0; c < NCLS; ++c) se += expf(lg[c] - m);
        float best = sobj / se;

        float r0 = s[21] + regb[0], r1 = s[22] + regb[1];
        float r2 = s[23] + regb[2], r3 = s[24] + regb[3];
        int gy = p / FMPX, gx = p - gy * FMPX;
        float cx = 1.f / (1.f + expf(-r0)) + (float)gx;
        float cy = 1.f / (1.f + expf(-r1)) + (float)gy;
        float hw = 0.5f * expf(r2);
        float hh = 0.5f * expf(r3);
        const float sc = 32.f / 1280.f;
        float x1 = fminf(fmaxf((cx - hw) * sc, 0.f), 1.f);
        float y1 = fminf(fmaxf((cy - hh) * sc, 0.f), 1.f);
        float x2 = fminf(fmaxf((cx + hw) * sc, 0.f), 1.f);
        float y2 = fminf(fmaxf((cy + hh) * sc, 0.f), 1.f);

        ((float4*)out)[gp] = make_float4(x1, y1, x2, y2);
        out[4 * BATCH * NP + gp] = best;
        out[5 * BATCH * NP + gp] = (float)am;
        out[6 * BATCH * NP + gp] = 0.f;
    }
}

// ---------------------------------------------------------------------------
// Sort-based greedy NMS, one block per (b,c). (unchanged from R2)
// ---------------------------------------------------------------------------
__global__ __launch_bounds__(256)
void nms_kernel(float* __restrict__ out) {
    const int c = blockIdx.x, b = blockIdx.y;
    const int t = threadIdx.x;
    const int w = t >> 6, l = t & 63;

    __shared__ unsigned long long skey[2048];
    __shared__ float4 CBox[NP];
    __shared__ float4 KBox[NP];
    __shared__ float4 CB64[64];
    __shared__ unsigned long long wmask[4];
    __shared__ int Kcnt;

    for (int j = t; j < NP; j += 256) {
        int gp = b * NP + j;
        float4 bx = ((const float4*)out)[gp];
        float best = out[4 * BATCH * NP + gp];
        int   ci   = (int)out[5 * BATCH * NP + gp];
        CBox[j] = bx;
        bool alive = (ci == c) && (best >= CONF_THR);
        unsigned long long key = alive
            ? ~(((unsigned long long)__float_as_uint(best) << 32)
                | (unsigned long long)(0xFFFFFFFFu - (unsigned)j))
            : ~0ull;
        skey[j] = key;
    }
    for (int j = NP + t; j < 2048; j += 256) skey[j] = ~0ull;
    if (t == 0) Kcnt = 0;

    for (unsigned k = 2; k <= 2048; k <<= 1) {
        for (unsigned j = k >> 1; j > 0; j >>= 1) {
            __syncthreads();
            for (unsigned i = t; i < 2048; i += 256) {
                unsigned p = i ^ j;
                if (p > i) {
                    bool up = ((i & k) == 0);
                    unsigned long long a = skey[i], bq = skey[p];
                    if ((a > bq) == up) { skey[i] = bq; skey[p] = a; }
                }
            }
        }
    }
    __syncthreads();

    float* keepout = out + 6 * BATCH * NP + b * NP;
    for (int base = 0; base < NP; base += 64) {
        unsigned long long ik = skey[base + l];
        bool valid = (ik != ~0ull);
        unsigned long long vm = __ballot(valid);
        if (vm == 0) break;

        unsigned idx = 0;
        float4 bx = make_float4(0.f, 0.f, 0.f, 0.f);
        float ar = 0.f;
        if (valid) {
            unsigned long long K = ~ik;
            idx = 0xFFFFFFFFu - (unsigned)(K & 0xFFFFFFFFull);
            bx  = CBox[idx];
            ar  = (bx.z - bx.x) * (bx.w - bx.y);
        }
        if (w == 0) CB64[l] = bx;
        int prevK = Kcnt;

        bool sup = false;
        for (int k = w; k < prevK; k += 4) {
            float4 kb = KBox[k];
            float kar = (kb.z - kb.x) * (kb.w - kb.y);
            float xx1 = fmaxf(kb.x, bx.x);
            float yy1 = fmaxf(kb.y, bx.y);
            float xx2 = fminf(kb.z, bx.z);
            float yy2 = fminf(kb.w, bx.w);
            float ww = fmaxf(1e-28f, xx2 - xx1);
            float hh = fmaxf(1e-28f, yy2 - yy1);
            float inter = ww * hh;
            float iou = inter / (kar + ar - inter + 1e-14f);
            sup |= (iou > NMS_THR);
        }
        wmask[w] = __ballot(valid && !sup);
        __syncthreads();

        if (w == 0) {
            unsigned long long alive = wmask[0] & wmask[1] & wmask[2] & wmask[3];
            unsigned long long smask = 0;
            for (int s = 0; s < 64; ++s) {
                float4 ob = CB64[s];
                float oar = (ob.z - ob.x) * (ob.w - ob.y);
                float xx1 = fmaxf(ob.x, bx.x);
                float yy1 = fmaxf(ob.y, bx.y);
                float xx2 = fminf(ob.z, bx.z);
                float yy2 = fminf(ob.w, bx.w);
                float ww = fmaxf(1e-28f, xx2 - xx1);
                float hh = fmaxf(1e-28f, yy2 - yy1);
                float inter = ww * hh;
                float iou = inter / (oar + ar - inter + 1e-14f);
                if (s < l && iou > NMS_THR) smask |= (1ull << s);
            }
            unsigned long long kept = 0;
            while (alive) {
                int s = __builtin_ctzll(alive);
                kept |= (1ull << s);
                alive &= ~(1ull << s);
                unsigned long long dead = __ballot((smask >> s) & 1ull);
                alive &= ~dead;
            }
            if ((kept >> l) & 1ull) {
                int pos = prevK + __builtin_popcountll(kept & ((1ull << l) - 1ull));
                KBox[pos] = bx;
                keepout[idx] = 1.0f;
            }
            if (l == 0) Kcnt = prevK + __builtin_popcountll(kept);
        }
        __syncthreads();
    }
}

// ---------------------------------------------------------------------------
extern "C" void kernel_launch(void* const* d_in, const int* in_sizes, int n_in,
                              void* d_out, int out_size, void* d_ws, size_t ws_size,
                              hipStream_t stream) {
    const float* x      = (const float*)d_in[0];
    const float* cls_w  = (const float*)d_in[1];
    const float* cls_b  = (const float*)d_in[2];
    const float* reg_w  = (const float*)d_in[3];
    const float* reg_b  = (const float*)d_in[4];
    const float* obj_w  = (const float*)d_in[5];
    const float* obj_b  = (const float*)d_in[6];
    const float* clsp_w = (const float*)d_in[7];
    const float* clsp_b = (const float*)d_in[8];
    const float* regp_w = (const float*)d_in[9];
    const float* regp_b = (const float*)d_in[10];
    float* out = (float*)d_out;

    _Float16* ws = (_Float16*)d_ws;
    _Float16* Xh = ws;                 // xp hi
    _Float16* Xl = ws + FPLANE;        // xp lo
    _Float16* Ah = ws + 2 * FPLANE;
    _Float16* Al = ws + 3 * FPLANE;
    _Float16* Bh = ws + 4 * FPLANE;
    _Float16* Bl = ws + 5 * FPLANE;
    _Float16* Wh = ws + 6 * FPLANE;
    _Float16* Wl = Wh + WSZ;
    const size_t LW = (size_t)CH * CH * 9;   // fp32 weight elems per layer

    border_zero<<<dim3(1968), 256, 0, stream>>>((uint4*)d_ws);
    xprep_kernel<<<dim3(25, 8, 8), 256, 0, stream>>>(x, Xh, Xl);

    dim3 wgrid(16, 16), cgrid(200, 2), blk(256);

    // cls chain: xp -> A -> B (cf = B)
    wtrans_kernel<<<wgrid, blk, 0, stream>>>(cls_w, Wh, Wl);
    conv_mfma<<<cgrid, blk, 0, stream>>>(Xh, Xl, Wh, Wl, cls_b,          Ah, Al);
    wtrans_kernel<<<wgrid, blk, 0, stream>>>(cls_w + LW, Wh, Wl);
    conv_mfma<<<cgrid, blk, 0, stream>>>(Ah, Al, Wh, Wl, cls_b + CH,     Bh, Bl);
    // reg chain: xp -> A -> xp -> A -> xp (rf = xp)
    wtrans_kernel<<<wgrid, blk, 0, stream>>>(reg_w, Wh, Wl);
    conv_mfma<<<cgrid, blk, 0, stream>>>(Xh, Xl, Wh, Wl, reg_b,          Ah, Al);
    wtrans_kernel<<<wgrid, blk, 0, stream>>>(reg_w + LW, Wh, Wl);
    conv_mfma<<<cgrid, blk, 0, stream>>>(Ah, Al, Wh, Wl, reg_b + CH,     Xh, Xl);
    wtrans_kernel<<<wgrid, blk, 0, stream>>>(reg_w + 2 * LW, Wh, Wl);
    conv_mfma<<<cgrid, blk, 0, stream>>>(Xh, Xl, Wh, Wl, reg_b + 2 * CH, Ah, Al);
    wtrans_kernel<<<wgrid, blk, 0, stream>>>(reg_w + 3 * LW, Wh, Wl);
    conv_mfma<<<cgrid, blk, 0, stream>>>(Ah, Al, Wh, Wl, reg_b + 3 * CH, Xh, Xl);

    head_kernel<<<dim3(3200), 256, 0, stream>>>(Xh, Xl, Bh, Bl, obj_w, obj_b,
                                                clsp_w, clsp_b, regp_w, regp_b, out);
    nms_kernel<<<dim3(NCLS, BATCH), 256, 0, stream>>>(out);
}

// Round 4
// 2513.103 us; speedup vs baseline: 3.7345x; 1.6075x over previous
//
#include <hip/hip_runtime.h>
#include <math.h>

#define CH    512
#define FMPX  40
#define PW    42            // padded row width
#define PADN  1764          // 42*42
#define NP    1600          // 40*40
#define BATCH 8
#define NCLS  20
#define CONF_THR 0.001f
#define NMS_THR  0.6f

typedef _Float16 v8h __attribute__((ext_vector_type(8)));
typedef float    v4f __attribute__((ext_vector_type(4)));

// ws layout (in _Float16 units). 6 feature planes contiguous, then weights.
#define FPLANE  ((size_t)BATCH * PADN * CH)          // 7,225,344 halves
#define WSZ     ((size_t)9 * CH * CH)                // 2,359,296 halves

__device__ __forceinline__ int padidx(int p) { return p + 2 * (p / FMPX) + PW + 1; }

// async global->LDS, 16 B per lane; LDS dest = base + lane*16 (wave-uniform base)
typedef __attribute__((address_space(1))) const void* gas_t;
typedef __attribute__((address_space(3))) void*       las_t;
__device__ __forceinline__ void gl2lds16(const void* g, void* l) {
    __builtin_amdgcn_global_load_lds((gas_t)g, (las_t)l, 16, 0, 0);
}

// ---------------------------------------------------------------------------
// Zero the padded borders of all 6 feature planes (ws re-poisoned each call).
// ---------------------------------------------------------------------------
__global__ __launch_bounds__(256)
void border_zero(uint4* __restrict__ ws) {
    int idx = blockIdx.x * 256 + threadIdx.x;           // grid 1968 blocks exact
    int u    = idx & 63;
    int cell = (idx >> 6) % 164;
    int b    = (idx / (64 * 164)) & 7;
    int pl   = idx / (64 * 164 * 8);
    int pi;
    if (cell < 42)      pi = cell;
    else if (cell < 84) pi = 41 * PW + (cell - 42);
    else { int r = cell - 84; pi = (1 + (r >> 1)) * PW + ((r & 1) ? 41 : 0); }
    size_t hoff = (size_t)pl * FPLANE + (size_t)b * (PADN * CH) + (size_t)pi * CH;
    ws[(hoff >> 3) + u] = make_uint4(0u, 0u, 0u, 0u);
}

// ---------------------------------------------------------------------------
// x [b][512][1600] fp32 -> padded pos-major fp16 hi/lo planes [b][1764][512].
// ---------------------------------------------------------------------------
__global__ __launch_bounds__(256)
void xprep_kernel(const float* __restrict__ x, _Float16* __restrict__ Xh,
                  _Float16* __restrict__ Xl) {
    __shared__ float T[64][65];
    const int t = threadIdx.x;
    const int p0  = blockIdx.x * 64;   // 25
    const int ci0 = blockIdx.y * 64;   // 8
    const int b   = blockIdx.z;        // 8
#pragma unroll
    for (int it = 0; it < 16; ++it) {
        int row = (t >> 6) + 4 * it;
        int col = t & 63;
        T[col][row] = x[((size_t)b * CH + ci0 + row) * NP + p0 + col];
    }
    __syncthreads();
#pragma unroll
    for (int it = 0; it < 16; ++it) {
        int posl = (t >> 6) + 4 * it;
        int ci   = t & 63;
        float v = T[posl][ci];
        _Float16 h = (_Float16)v;
        _Float16 l = (_Float16)((v - (float)h) * 2048.0f);
        size_t o = (size_t)b * (PADN * CH) + (size_t)padidx(p0 + posl) * CH + ci0 + ci;
        Xh[o] = h; Xl[o] = l;
    }
}

// ---------------------------------------------------------------------------
// w [co][ci][3][3] fp32 -> Wh/Wl [tap][co][ci] fp16.
// ---------------------------------------------------------------------------
__global__ __launch_bounds__(256)
void wtrans_kernel(const float* __restrict__ w, _Float16* __restrict__ Wh,
                   _Float16* __restrict__ Wl) {
    __shared__ float tile[32][289];
    const int t = threadIdx.x;
    const int co0 = blockIdx.x * 32;   // 16
    const int ci0 = blockIdx.y * 32;   // 16
#pragma unroll
    for (int g = 0; g < 36; ++g) {     // 32*288 = 9216
        int l = t + 256 * g;
        int co = l / 288, j = l - co * 288;
        tile[co][j] = w[(size_t)(co0 + co) * 4608 + ci0 * 9 + j];
    }
    __syncthreads();
#pragma unroll
    for (int tap = 0; tap < 9; ++tap) {
#pragma unroll
        for (int cg = 0; cg < 4; ++cg) {
            int co = cg * 8 + (t >> 5);
            int ci = t & 31;
            float v = tile[co][ci * 9 + tap];
            _Float16 h = (_Float16)(16.0f * v);
            _Float16 l = (_Float16)((v - (float)h * 0.0625f) * 32768.0f);
            size_t o = ((size_t)tap * CH + co0 + co) * CH + ci0 + ci;
            Wh[o] = h; Wl[o] = l;
        }
    }
}

// ---------------------------------------------------------------------------
// 3x3 conv via MFMA, split-fp16, m97-style LDS staging.
// Block 256 thr = 4 waves; block tile M=64 pos x N=256 co; wave 64x64.
// Fragment-ordered LDS: global_load_lds(16B/lane) writes exactly the MFMA
// fragment each lane will ds_read_b128 back (lane-consecutive, conflict-free).
// LDS map (halves): As_h[0,2048) As_l[2048,4096) Bs_h[4096,12288) Bs_l[12288,20480)
// Per K=32 chunk: 10 global_load_lds + 2 barriers + 16 ds_read_b128 + 48 MFMA /wave.
// ---------------------------------------------------------------------------
__global__ __launch_bounds__(256, 2)
void conv_mfma(const _Float16* __restrict__ Ih, const _Float16* __restrict__ Il,
               const _Float16* __restrict__ Wh, const _Float16* __restrict__ Wl,
               const float* __restrict__ bias,
               _Float16* __restrict__ Oh, _Float16* __restrict__ Ol) {
    __shared__ _Float16 sm[20480];   // 40 KB
    const int t = threadIdx.x;
    const int w = t >> 6, l = t & 63;
    const int quad = l >> 4, col = l & 15;
    const int bx = blockIdx.x;               // 0..199 = b*25 + ptile
    const int b  = bx / 25;
    const int p0 = (bx - b * 25) * 64;
    const int co0 = blockIdx.y * 256;        // gridDim.y = 2
    const size_t boff = (size_t)b * (PADN * CH);

    // ---- staging source offsets (halves), lane-dependent ----
    // A tile i=w: pos = p0 + w*16 + col, ci-sub = quad*8
    const size_t aG = boff + (size_t)padidx(p0 + w * 16 + col) * CH + quad * 8;
    // B tiles j: co = co0 + w*64 + j*16 + col
    size_t bG[4];
#pragma unroll
    for (int j = 0; j < 4; ++j)
        bG[j] = (size_t)(co0 + w * 64 + j * 16 + col) * CH + quad * 8;

    // ---- LDS staging dests ----
    _Float16* aDh = sm + (size_t)(w * 64 + l) * 8;
    _Float16* aDl = aDh + 2048;
    _Float16* bDh[4];
#pragma unroll
    for (int j = 0; j < 4; ++j) bDh[j] = sm + 4096 + (size_t)((w * 4 + j) * 64 + l) * 8;

    v4f acc1[4][4], acc2[4][4];
#pragma unroll
    for (int i = 0; i < 4; ++i)
#pragma unroll
        for (int j = 0; j < 4; ++j) {
            acc1[i][j] = (v4f){0.f, 0.f, 0.f, 0.f};
            acc2[i][j] = (v4f){0.f, 0.f, 0.f, 0.f};
        }

    for (int tap = 0; tap < 9; ++tap) {
        const int dy = tap / 3 - 1, dx = tap - (tap / 3) * 3 - 1;
        const int tsh = (dy * PW + dx) * CH;
        const _Float16* gAh = Ih + aG + tsh;
        const _Float16* gAl = Il + aG + tsh;
        const _Float16* gWh = Wh + (size_t)tap * (CH * CH);
        const _Float16* gWl = Wl + (size_t)tap * (CH * CH);
        for (int kc = 0; kc < 16; ++kc) {
            const int c0 = kc * 32;
            __syncthreads();                 // prev chunk's LDS reads done
            gl2lds16(gAh + c0, aDh);
            gl2lds16(gAl + c0, aDl);
#pragma unroll
            for (int j = 0; j < 4; ++j) {
                gl2lds16(gWh + bG[j] + c0, bDh[j]);
                gl2lds16(gWl + bG[j] + c0, bDh[j] + 8192);
            }
            asm volatile("s_waitcnt vmcnt(0)" ::: "memory");
            __syncthreads();                 // staged data visible

            v8h ah[4], al[4];
#pragma unroll
            for (int i = 0; i < 4; ++i) {
                ah[i] = *(const v8h*)(sm + (size_t)(i * 64 + l) * 8);
                al[i] = *(const v8h*)(sm + 2048 + (size_t)(i * 64 + l) * 8);
            }
#pragma unroll
            for (int j = 0; j < 4; ++j) {
                v8h bh = *(const v8h*)(sm + 4096  + (size_t)((w * 4 + j) * 64 + l) * 8);
                v8h bl = *(const v8h*)(sm + 12288 + (size_t)((w * 4 + j) * 64 + l) * 8);
#pragma unroll
                for (int i = 0; i < 4; ++i)
                    acc1[i][j] = __builtin_amdgcn_mfma_f32_16x16x32_f16(ah[i], bh, acc1[i][j], 0, 0, 0);
#pragma unroll
                for (int i = 0; i < 4; ++i)
                    acc2[i][j] = __builtin_amdgcn_mfma_f32_16x16x32_f16(ah[i], bl, acc2[i][j], 0, 0, 0);
#pragma unroll
                for (int i = 0; i < 4; ++i)
                    acc2[i][j] = __builtin_amdgcn_mfma_f32_16x16x32_f16(al[i], bh, acc2[i][j], 0, 0, 0);
            }
        }
    }

    // epilogue: combine, bias, leaky, split-store. wave covers co0+w*64 .. +63
#pragma unroll
    for (int i = 0; i < 4; ++i) {
#pragma unroll
        for (int j = 0; j < 4; ++j) {
            int n = co0 + w * 64 + j * 16 + col;
            float bv = bias[n];
#pragma unroll
            for (int r = 0; r < 4; ++r) {
                int p = p0 + i * 16 + quad * 4 + r;
                float v = acc1[i][j][r] * 0.0625f + acc2[i][j][r] * (1.0f / 32768.0f) + bv;
                v = v > 0.f ? v : 0.1f * v;
                _Float16 h = (_Float16)v;
                _Float16 lo = (_Float16)((v - (float)h) * 2048.0f);
                size_t o = boff + (size_t)padidx(p) * CH + n;
                Oh[o] = h; Ol[o] = lo;
            }
        }
    }
}

// ---------------------------------------------------------------------------
// Head: 1x1 convs + decode. One wave per (b,pos); lanes split ci (64x8=512).
// ---------------------------------------------------------------------------
__global__ __launch_bounds__(256)
void head_kernel(const _Float16* __restrict__ Rh, const _Float16* __restrict__ Rl,
                 const _Float16* __restrict__ Ch, const _Float16* __restrict__ Cl,
                 const float* __restrict__ objw, const float* __restrict__ objb,
                 const float* __restrict__ clsw, const float* __restrict__ clsb,
                 const float* __restrict__ regw, const float* __restrict__ regb,
                 float* __restrict__ out) {
    const int wid = (blockIdx.x * 256 + threadIdx.x) >> 6;  // 0..12799
    const int l = threadIdx.x & 63;
    const int b = wid / NP, p = wid - b * NP;
    const size_t base = (size_t)b * (PADN * CH) + (size_t)padidx(p) * CH + l * 8;

    v8h rh = *(const v8h*)(Rh + base), rl = *(const v8h*)(Rl + base);
    v8h ch = *(const v8h*)(Ch + base), cl = *(const v8h*)(Cl + base);
    float rv[8], cv[8];
#pragma unroll
    for (int k = 0; k < 8; ++k) {
        rv[k] = (float)rh[k] + (float)rl[k] * (1.0f / 2048.0f);
        cv[k] = (float)ch[k] + (float)cl[k] * (1.0f / 2048.0f);
    }
    float s[25];
#pragma unroll
    for (int o = 0; o < 25; ++o) s[o] = 0.f;
#pragma unroll
    for (int k = 0; k < 8; ++k) s[0] = fmaf(objw[l * 8 + k], rv[k], s[0]);
#pragma unroll
    for (int c = 0; c < NCLS; ++c)
#pragma unroll
        for (int k = 0; k < 8; ++k) s[1 + c] = fmaf(clsw[c * CH + l * 8 + k], cv[k], s[1 + c]);
#pragma unroll
    for (int q = 0; q < 4; ++q)
#pragma unroll
        for (int k = 0; k < 8; ++k) s[21 + q] = fmaf(regw[q * CH + l * 8 + k], rv[k], s[21 + q]);
#pragma unroll
    for (int o = 0; o < 25; ++o) {
#pragma unroll
        for (int off = 32; off > 0; off >>= 1) s[o] += __shfl_xor(s[o], off);
    }
    if (l == 0) {
        int gp = b * NP + p;
        float obj  = s[0] + objb[0];
        float sobj = 1.f / (1.f + expf(-obj));
        float lg[NCLS];
        float m = -1e30f; int am = 0;
#pragma unroll
        for (int c = 0; c < NCLS; ++c) {
            lg[c] = s[1 + c] + clsb[c];
            if (lg[c] > m) { m = lg[c]; am = c; }
        }
        float se = 0.f;
#pragma unroll
        for (int c = 0; c < NCLS; ++c) se += expf(lg[c] - m);
        float best = sobj / se;

        float r0 = s[21] + regb[0], r1 = s[22] + regb[1];
        float r2 = s[23] + regb[2], r3 = s[24] + regb[3];
        int gy = p / FMPX, gx = p - gy * FMPX;
        float cx = 1.f / (1.f + expf(-r0)) + (float)gx;
        float cy = 1.f / (1.f + expf(-r1)) + (float)gy;
        float hw = 0.5f * expf(r2);
        float hh = 0.5f * expf(r3);
        const float sc = 32.f / 1280.f;
        float x1 = fminf(fmaxf((cx - hw) * sc, 0.f), 1.f);
        float y1 = fminf(fmaxf((cy - hh) * sc, 0.f), 1.f);
        float x2 = fminf(fmaxf((cx + hw) * sc, 0.f), 1.f);
        float y2 = fminf(fmaxf((cy + hh) * sc, 0.f), 1.f);

        ((float4*)out)[gp] = make_float4(x1, y1, x2, y2);
        out[4 * BATCH * NP + gp] = best;
        out[5 * BATCH * NP + gp] = (float)am;
        out[6 * BATCH * NP + gp] = 0.f;
    }
}

// ---------------------------------------------------------------------------
// Sort-based greedy NMS, one block per (b,c). (unchanged)
// ---------------------------------------------------------------------------
__global__ __launch_bounds__(256)
void nms_kernel(float* __restrict__ out) {
    const int c = blockIdx.x, b = blockIdx.y;
    const int t = threadIdx.x;
    const int w = t >> 6, l = t & 63;

    __shared__ unsigned long long skey[2048];
    __shared__ float4 CBox[NP];
    __shared__ float4 KBox[NP];
    __shared__ float4 CB64[64];
    __shared__ unsigned long long wmask[4];
    __shared__ int Kcnt;

    for (int j = t; j < NP; j += 256) {
        int gp = b * NP + j;
        float4 bx = ((const float4*)out)[gp];
        float best = out[4 * BATCH * NP + gp];
        int   ci   = (int)out[5 * BATCH * NP + gp];
        CBox[j] = bx;
        bool alive = (ci == c) && (best >= CONF_THR);
        unsigned long long key = alive
            ? ~(((unsigned long long)__float_as_uint(best) << 32)
                | (unsigned long long)(0xFFFFFFFFu - (unsigned)j))
            : ~0ull;
        skey[j] = key;
    }
    for (int j = NP + t; j < 2048; j += 256) skey[j] = ~0ull;
    if (t == 0) Kcnt = 0;

    for (unsigned k = 2; k <= 2048; k <<= 1) {
        for (unsigned j = k >> 1; j > 0; j >>= 1) {
            __syncthreads();
            for (unsigned i = t; i < 2048; i += 256) {
                unsigned p = i ^ j;
                if (p > i) {
                    bool up = ((i & k) == 0);
                    unsigned long long a = skey[i], bq = skey[p];
                    if ((a > bq) == up) { skey[i] = bq; skey[p] = a; }
                }
            }
        }
    }
    __syncthreads();

    float* keepout = out + 6 * BATCH * NP + b * NP;
    for (int base = 0; base < NP; base += 64) {
        unsigned long long ik = skey[base + l];
        bool valid = (ik != ~0ull);
        unsigned long long vm = __ballot(valid);
        if (vm == 0) break;

        unsigned idx = 0;
        float4 bx = make_float4(0.f, 0.f, 0.f, 0.f);
        float ar = 0.f;
        if (valid) {
            unsigned long long K = ~ik;
            idx = 0xFFFFFFFFu - (unsigned)(K & 0xFFFFFFFFull);
            bx  = CBox[idx];
            ar  = (bx.z - bx.x) * (bx.w - bx.y);
        }
        if (w == 0) CB64[l] = bx;
        int prevK = Kcnt;

        bool sup = false;
        for (int k = w; k < prevK; k += 4) {
            float4 kb = KBox[k];
            float kar = (kb.z - kb.x) * (kb.w - kb.y);
            float xx1 = fmaxf(kb.x, bx.x);
            float yy1 = fmaxf(kb.y, bx.y);
            float xx2 = fminf(kb.z, bx.z);
            float yy2 = fminf(kb.w, bx.w);
            float ww = fmaxf(1e-28f, xx2 - xx1);
            float hh = fmaxf(1e-28f, yy2 - yy1);
            float inter = ww * hh;
            float iou = inter / (kar + ar - inter + 1e-14f);
            sup |= (iou > NMS_THR);
        }
        wmask[w] = __ballot(valid && !sup);
        __syncthreads();

        if (w == 0) {
            unsigned long long alive = wmask[0] & wmask[1] & wmask[2] & wmask[3];
            unsigned long long smask = 0;
            for (int s = 0; s < 64; ++s) {
                float4 ob = CB64[s];
                float oar = (ob.z - ob.x) * (ob.w - ob.y);
                float xx1 = fmaxf(ob.x, bx.x);
                float yy1 = fmaxf(ob.y, bx.y);
                float xx2 = fminf(ob.z, bx.z);
                float yy2 = fminf(ob.w, bx.w);
                float ww = fmaxf(1e-28f, xx2 - xx1);
                float hh = fmaxf(1e-28f, yy2 - yy1);
                float inter = ww * hh;
                float iou = inter / (oar + ar - inter + 1e-14f);
                if (s < l && iou > NMS_THR) smask |= (1ull << s);
            }
            unsigned long long kept = 0;
            while (alive) {
                int s = __builtin_ctzll(alive);
                kept |= (1ull << s);
                alive &= ~(1ull << s);
                unsigned long long dead = __ballot((smask >> s) & 1ull);
                alive &= ~dead;
            }
            if ((kept >> l) & 1ull) {
                int pos = prevK + __builtin_popcountll(kept & ((1ull << l) - 1ull));
                KBox[pos] = bx;
                keepout[idx] = 1.0f;
            }
            if (l == 0) Kcnt = prevK + __builtin_popcountll(kept);
        }
        __syncthreads();
    }
}

// ---------------------------------------------------------------------------
extern "C" void kernel_launch(void* const* d_in, const int* in_sizes, int n_in,
                              void* d_out, int out_size, void* d_ws, size_t ws_size,
                              hipStream_t stream) {
    const float* x      = (const float*)d_in[0];
    const float* cls_w  = (const float*)d_in[1];
    const float* cls_b  = (const float*)d_in[2];
    const float* reg_w  = (const float*)d_in[3];
    const float* reg_b  = (const float*)d_in[4];
    const float* obj_w  = (const float*)d_in[5];
    const float* obj_b  = (const float*)d_in[6];
    const float* clsp_w = (const float*)d_in[7];
    const float* clsp_b = (const float*)d_in[8];
    const float* regp_w = (const float*)d_in[9];
    const float* regp_b = (const float*)d_in[10];
    float* out = (float*)d_out;

    _Float16* ws = (_Float16*)d_ws;
    _Float16* Xh = ws;
    _Float16* Xl = ws + FPLANE;
    _Float16* Ah = ws + 2 * FPLANE;
    _Float16* Al = ws + 3 * FPLANE;
    _Float16* Bh = ws + 4 * FPLANE;
    _Float16* Bl = ws + 5 * FPLANE;
    _Float16* Wh = ws + 6 * FPLANE;
    _Float16* Wl = Wh + WSZ;
    const size_t LW = (size_t)CH * CH * 9;

    border_zero<<<dim3(1968), 256, 0, stream>>>((uint4*)d_ws);
    xprep_kernel<<<dim3(25, 8, 8), 256, 0, stream>>>(x, Xh, Xl);

    dim3 wgrid(16, 16), cgrid(200, 2), blk(256);

    // cls chain: xp -> A -> B (cf = B)
    wtrans_kernel<<<wgrid, blk, 0, stream>>>(cls_w, Wh, Wl);
    conv_mfma<<<cgrid, blk, 0, stream>>>(Xh, Xl, Wh, Wl, cls_b,          Ah, Al);
    wtrans_kernel<<<wgrid, blk, 0, stream>>>(cls_w + LW, Wh, Wl);
    conv_mfma<<<cgrid, blk, 0, stream>>>(Ah, Al, Wh, Wl, cls_b + CH,     Bh, Bl);
    // reg chain: xp -> A -> xp -> A -> xp (rf = xp)
    wtrans_kernel<<<wgrid, blk, 0, stream>>>(reg_w, Wh, Wl);
    conv_mfma<<<cgrid, blk, 0, stream>>>(Xh, Xl, Wh, Wl, reg_b,          Ah, Al);
    wtrans_kernel<<<wgrid, blk, 0, stream>>>(reg_w + LW, Wh, Wl);
    conv_mfma<<<cgrid, blk, 0, stream>>>(Ah, Al, Wh, Wl, reg_b + CH,     Xh, Xl);
    wtrans_kernel<<<wgrid, blk, 0, stream>>>(reg_w + 2 * LW, Wh, Wl);
    conv_mfma<<<cgrid, blk, 0, stream>>>(Xh, Xl, Wh, Wl, reg_b + 2 * CH, Ah, Al);
    wtrans_kernel<<<wgrid, blk, 0, stream>>>(reg_w + 3 * LW, Wh, Wl);
    conv_mfma<<<cgrid, blk, 0, stream>>>(Ah, Al, Wh, Wl, reg_b + 3 * CH, Xh, Xl);

    head_kernel<<<dim3(3200), 256, 0, stream>>>(Xh, Xl, Bh, Bl, obj_w, obj_b,
                                                clsp_w, clsp_b, regp_w, regp_b, out);
    nms_kernel<<<dim3(NCLS, BATCH), 256, 0, stream>>>(out);
}

// Round 5
// 2414.978 us; speedup vs baseline: 3.8863x; 1.0406x over previous
//
#include <hip/hip_runtime.h>
#include <math.h>

#define CH    512
#define FMPX  40
#define PW    42            // padded row width
#define PADN  1764          // 42*42
#define NP    1600          // 40*40
#define BATCH 8
#define NCLS  20
#define CONF_THR 0.001f
#define NMS_THR  0.6f

typedef _Float16 v8h __attribute__((ext_vector_type(8)));
typedef float    v4f __attribute__((ext_vector_type(4)));

// ws layout (in _Float16 units). 6 feature planes contiguous, then weights.
#define FPLANE  ((size_t)BATCH * PADN * CH)          // 7,225,344 halves
#define WSZ     ((size_t)9 * CH * CH)                // 2,359,296 halves

__device__ __forceinline__ int padidx(int p) { return p + 2 * (p / FMPX) + PW + 1; }

// async global->LDS, 16 B per lane; LDS dest = base + lane*16 (wave-uniform base)
typedef __attribute__((address_space(1))) const void* gas_t;
typedef __attribute__((address_space(3))) void*       las_t;
__device__ __forceinline__ void gl2lds16(const void* g, void* l) {
    __builtin_amdgcn_global_load_lds((gas_t)g, (las_t)l, 16, 0, 0);
}

// ---------------------------------------------------------------------------
// Zero the padded borders of all 6 feature planes (ws re-poisoned each call).
// ---------------------------------------------------------------------------
__global__ __launch_bounds__(256)
void border_zero(uint4* __restrict__ ws) {
    int idx = blockIdx.x * 256 + threadIdx.x;           // grid 1968 blocks exact
    int u    = idx & 63;
    int cell = (idx >> 6) % 164;
    int b    = (idx / (64 * 164)) & 7;
    int pl   = idx / (64 * 164 * 8);
    int pi;
    if (cell < 42)      pi = cell;
    else if (cell < 84) pi = 41 * PW + (cell - 42);
    else { int r = cell - 84; pi = (1 + (r >> 1)) * PW + ((r & 1) ? 41 : 0); }
    size_t hoff = (size_t)pl * FPLANE + (size_t)b * (PADN * CH) + (size_t)pi * CH;
    ws[(hoff >> 3) + u] = make_uint4(0u, 0u, 0u, 0u);
}

// ---------------------------------------------------------------------------
// x [b][512][1600] fp32 -> padded pos-major fp16 hi/lo planes [b][1764][512].
// ---------------------------------------------------------------------------
__global__ __launch_bounds__(256)
void xprep_kernel(const float* __restrict__ x, _Float16* __restrict__ Xh,
                  _Float16* __restrict__ Xl) {
    __shared__ float T[64][65];
    const int t = threadIdx.x;
    const int p0  = blockIdx.x * 64;   // 25
    const int ci0 = blockIdx.y * 64;   // 8
    const int b   = blockIdx.z;        // 8
#pragma unroll
    for (int it = 0; it < 16; ++it) {
        int row = (t >> 6) + 4 * it;
        int col = t & 63;
        T[col][row] = x[((size_t)b * CH + ci0 + row) * NP + p0 + col];
    }
    __syncthreads();
#pragma unroll
    for (int it = 0; it < 16; ++it) {
        int posl = (t >> 6) + 4 * it;
        int ci   = t & 63;
        float v = T[posl][ci];
        _Float16 h = (_Float16)v;
        _Float16 l = (_Float16)((v - (float)h) * 2048.0f);
        size_t o = (size_t)b * (PADN * CH) + (size_t)padidx(p0 + posl) * CH + ci0 + ci;
        Xh[o] = h; Xl[o] = l;
    }
}

// ---------------------------------------------------------------------------
// w [co][ci][3][3] fp32 -> Wh/Wl [tap][co][ci] fp16.
// ---------------------------------------------------------------------------
__global__ __launch_bounds__(256)
void wtrans_kernel(const float* __restrict__ w, _Float16* __restrict__ Wh,
                   _Float16* __restrict__ Wl) {
    __shared__ float tile[32][289];
    const int t = threadIdx.x;
    const int co0 = blockIdx.x * 32;   // 16
    const int ci0 = blockIdx.y * 32;   // 16
#pragma unroll
    for (int g = 0; g < 36; ++g) {     // 32*288 = 9216
        int l = t + 256 * g;
        int co = l / 288, j = l - co * 288;
        tile[co][j] = w[(size_t)(co0 + co) * 4608 + ci0 * 9 + j];
    }
    __syncthreads();
#pragma unroll
    for (int tap = 0; tap < 9; ++tap) {
#pragma unroll
        for (int cg = 0; cg < 4; ++cg) {
            int co = cg * 8 + (t >> 5);
            int ci = t & 31;
            float v = tile[co][ci * 9 + tap];
            _Float16 h = (_Float16)(16.0f * v);
            _Float16 l = (_Float16)((v - (float)h * 0.0625f) * 32768.0f);
            size_t o = ((size_t)tap * CH + co0 + co) * CH + ci0 + ci;
            Wh[o] = h; Wl[o] = l;
        }
    }
}

// ---------------------------------------------------------------------------
// 3x3 conv via MFMA, split-fp16, double-buffered LDS pipeline (raw s_barrier
// + fine vmcnt(10) — loads for chunk k+1 stay in flight across compute of k).
// Block 256 thr = 4 waves; tile M=64 pos x N=256 co; wave 64x64 of 16x16x32.
// LDS per buf (halves): A_h[0,2048) A_l[2048,4096) B_h[4096,12288) B_l[12288,20480)
// 2 bufs = 80 KB -> 2 blocks/CU.
// ---------------------------------------------------------------------------
__global__ __launch_bounds__(256, 2)
void conv_mfma(const _Float16* __restrict__ Ih, const _Float16* __restrict__ Il,
               const _Float16* __restrict__ Wh, const _Float16* __restrict__ Wl,
               const float* __restrict__ bias,
               _Float16* __restrict__ Oh, _Float16* __restrict__ Ol) {
    __shared__ _Float16 sm[2][20480];   // 80 KB
    const int t = threadIdx.x;
    const int w = t >> 6, l = t & 63;
    const int quad = l >> 4, col = l & 15;
    const int bx = blockIdx.x;               // 0..199 = b*25 + ptile
    const int b  = bx / 25;
    const int p0 = (bx - b * 25) * 64;
    const int co0 = blockIdx.y * 256;        // gridDim.y = 2
    const size_t boff = (size_t)b * (PADN * CH);

    // lane-dependent global source offsets (halves)
    const size_t aG = boff + (size_t)padidx(p0 + w * 16 + col) * CH + quad * 8;
    size_t bG[4];
#pragma unroll
    for (int j = 0; j < 4; ++j)
        bG[j] = (size_t)(co0 + w * 64 + j * 16 + col) * CH + quad * 8;

    // LDS staging dest offsets (halves, relative to buffer base)
    const int aD = (w * 64 + l) * 8;
    int bD[4];
#pragma unroll
    for (int j = 0; j < 4; ++j) bD[j] = 4096 + ((w * 4 + j) * 64 + l) * 8;

    v4f acc1[4][4], acc2[4][4];
#pragma unroll
    for (int i = 0; i < 4; ++i)
#pragma unroll
        for (int j = 0; j < 4; ++j) {
            acc1[i][j] = (v4f){0.f, 0.f, 0.f, 0.f};
            acc2[i][j] = (v4f){0.f, 0.f, 0.f, 0.f};
        }

    // issue the 10 staging loads for chunk c into buffer buf
    auto issue = [&](int c, int buf) {
        const int tap = c >> 4;
        const int c0  = (c & 15) * 32;
        const int ty = tap / 3, tx = tap - 3 * ty;
        const int tsh = ((ty - 1) * PW + (tx - 1)) * CH;
        _Float16* base = sm[buf];
        gl2lds16(Ih + aG + tsh + c0, base + aD);
        gl2lds16(Il + aG + tsh + c0, base + 2048 + aD);
        const _Float16* gWh = Wh + (size_t)tap * (CH * CH) + c0;
        const _Float16* gWl = Wl + (size_t)tap * (CH * CH) + c0;
#pragma unroll
        for (int j = 0; j < 4; ++j) {
            gl2lds16(gWh + bG[j], base + bD[j]);
            gl2lds16(gWl + bG[j], base + 8192 + bD[j]);
        }
    };

    issue(0, 0);
#pragma unroll 1
    for (int c = 0; c < 144; ++c) {
        // all waves done reading buf[(c+1)&1] (chunk c-1) -> safe to overwrite
        asm volatile("s_barrier" ::: "memory");
        if (c + 1 < 144) {
            issue(c + 1, (c + 1) & 1);
            asm volatile("s_waitcnt vmcnt(10)" ::: "memory");  // chunk c staged
        } else {
            asm volatile("s_waitcnt vmcnt(0)" ::: "memory");
        }
        asm volatile("s_barrier" ::: "memory");                // staged data visible

        const _Float16* S = sm[c & 1];
        v8h ah[4], al[4];
#pragma unroll
        for (int i = 0; i < 4; ++i) {
            ah[i] = *(const v8h*)(S + (i * 64 + l) * 8);
            al[i] = *(const v8h*)(S + 2048 + (i * 64 + l) * 8);
        }
#pragma unroll
        for (int j = 0; j < 4; ++j) {
            v8h bh = *(const v8h*)(S + 4096  + ((w * 4 + j) * 64 + l) * 8);
            v8h bl = *(const v8h*)(S + 12288 + ((w * 4 + j) * 64 + l) * 8);
#pragma unroll
            for (int i = 0; i < 4; ++i)
                acc1[i][j] = __builtin_amdgcn_mfma_f32_16x16x32_f16(ah[i], bh, acc1[i][j], 0, 0, 0);
#pragma unroll
            for (int i = 0; i < 4; ++i)
                acc2[i][j] = __builtin_amdgcn_mfma_f32_16x16x32_f16(ah[i], bl, acc2[i][j], 0, 0, 0);
#pragma unroll
            for (int i = 0; i < 4; ++i)
                acc2[i][j] = __builtin_amdgcn_mfma_f32_16x16x32_f16(al[i], bh, acc2[i][j], 0, 0, 0);
        }
    }

    // epilogue: combine, bias, leaky, split-store. wave covers co0+w*64 .. +63
#pragma unroll
    for (int i = 0; i < 4; ++i) {
#pragma unroll
        for (int j = 0; j < 4; ++j) {
            int n = co0 + w * 64 + j * 16 + col;
            float bv = bias[n];
#pragma unroll
            for (int r = 0; r < 4; ++r) {
                int p = p0 + i * 16 + quad * 4 + r;
                float v = acc1[i][j][r] * 0.0625f + acc2[i][j][r] * (1.0f / 32768.0f) + bv;
                v = v > 0.f ? v : 0.1f * v;
                _Float16 h = (_Float16)v;
                _Float16 lo = (_Float16)((v - (float)h) * 2048.0f);
                size_t o = boff + (size_t)padidx(p) * CH + n;
                Oh[o] = h; Ol[o] = lo;
            }
        }
    }
}

// ---------------------------------------------------------------------------
// Head: 1x1 convs + decode. One wave per (b,pos); lanes split ci (64x8=512).
// ---------------------------------------------------------------------------
__global__ __launch_bounds__(256)
void head_kernel(const _Float16* __restrict__ Rh, const _Float16* __restrict__ Rl,
                 const _Float16* __restrict__ Ch, const _Float16* __restrict__ Cl,
                 const float* __restrict__ objw, const float* __restrict__ objb,
                 const float* __restrict__ clsw, const float* __restrict__ clsb,
                 const float* __restrict__ regw, const float* __restrict__ regb,
                 float* __restrict__ out) {
    const int wid = (blockIdx.x * 256 + threadIdx.x) >> 6;  // 0..12799
    const int l = threadIdx.x & 63;
    const int b = wid / NP, p = wid - b * NP;
    const size_t base = (size_t)b * (PADN * CH) + (size_t)padidx(p) * CH + l * 8;

    v8h rh = *(const v8h*)(Rh + base), rl = *(const v8h*)(Rl + base);
    v8h ch = *(const v8h*)(Ch + base), cl = *(const v8h*)(Cl + base);
    float rv[8], cv[8];
#pragma unroll
    for (int k = 0; k < 8; ++k) {
        rv[k] = (float)rh[k] + (float)rl[k] * (1.0f / 2048.0f);
        cv[k] = (float)ch[k] + (float)cl[k] * (1.0f / 2048.0f);
    }
    float s[25];
#pragma unroll
    for (int o = 0; o < 25; ++o) s[o] = 0.f;
#pragma unroll
    for (int k = 0; k < 8; ++k) s[0] = fmaf(objw[l * 8 + k], rv[k], s[0]);
#pragma unroll
    for (int c = 0; c < NCLS; ++c)
#pragma unroll
        for (int k = 0; k < 8; ++k) s[1 + c] = fmaf(clsw[c * CH + l * 8 + k], cv[k], s[1 + c]);
#pragma unroll
    for (int q = 0; q < 4; ++q)
#pragma unroll
        for (int k = 0; k < 8; ++k) s[21 + q] = fmaf(regw[q * CH + l * 8 + k], rv[k], s[21 + q]);
#pragma unroll
    for (int o = 0; o < 25; ++o) {
#pragma unroll
        for (int off = 32; off > 0; off >>= 1) s[o] += __shfl_xor(s[o], off);
    }
    if (l == 0) {
        int gp = b * NP + p;
        float obj  = s[0] + objb[0];
        float sobj = 1.f / (1.f + expf(-obj));
        float lg[NCLS];
        float m = -1e30f; int am = 0;
#pragma unroll
        for (int c = 0; c < NCLS; ++c) {
            lg[c] = s[1 + c] + clsb[c];
            if (lg[c] > m) { m = lg[c]; am = c; }
        }
        float se = 0.f;
#pragma unroll
        for (int c = 0; c < NCLS; ++c) se += expf(lg[c] - m);
        float best = sobj / se;

        float r0 = s[21] + regb[0], r1 = s[22] + regb[1];
        float r2 = s[23] + regb[2], r3 = s[24] + regb[3];
        int gy = p / FMPX, gx = p - gy * FMPX;
        float cx = 1.f / (1.f + expf(-r0)) + (float)gx;
        float cy = 1.f / (1.f + expf(-r1)) + (float)gy;
        float hw = 0.5f * expf(r2);
        float hh = 0.5f * expf(r3);
        const float sc = 32.f / 1280.f;
        float x1 = fminf(fmaxf((cx - hw) * sc, 0.f), 1.f);
        float y1 = fminf(fmaxf((cy - hh) * sc, 0.f), 1.f);
        float x2 = fminf(fmaxf((cx + hw) * sc, 0.f), 1.f);
        float y2 = fminf(fmaxf((cy + hh) * sc, 0.f), 1.f);

        ((float4*)out)[gp] = make_float4(x1, y1, x2, y2);
        out[4 * BATCH * NP + gp] = best;
        out[5 * BATCH * NP + gp] = (float)am;
        out[6 * BATCH * NP + gp] = 0.f;
    }
}

// ---------------------------------------------------------------------------
// Sort-based greedy NMS v2: 1024 threads (16 waves), MLP kept-scan over a
// zero-padded kept array (4 consecutive b128 broadcasts per wave per iter),
// shfl-based intra-chunk resolution (no LDS in the serial loop).
// ---------------------------------------------------------------------------
__global__ __launch_bounds__(1024)
void nms_kernel(float* __restrict__ out) {
    const int c = blockIdx.x, b = blockIdx.y;
    const int t = threadIdx.x;
    const int w = t >> 6, l = t & 63;

    __shared__ unsigned long long skey[2048];
    __shared__ float4 CBox[NP];
    __shared__ float4 KBox[1664];       // kept, zero-padded to x64
    __shared__ unsigned long long wmask[16];
    __shared__ int Kcnt;

    for (int j = t; j < NP; j += 1024) {
        int gp = b * NP + j;
        float4 bx = ((const float4*)out)[gp];
        float best = out[4 * BATCH * NP + gp];
        int   ci   = (int)out[5 * BATCH * NP + gp];
        CBox[j] = bx;
        bool alive = (ci == c) && (best >= CONF_THR);
        unsigned long long key = alive
            ? ~(((unsigned long long)__float_as_uint(best) << 32)
                | (unsigned long long)(0xFFFFFFFFu - (unsigned)j))
            : ~0ull;
        skey[j] = key;
    }
    for (int j = NP + t; j < 2048; j += 1024) skey[j] = ~0ull;
    for (int j = t; j < 1664; j += 1024) KBox[j] = make_float4(0.f, 0.f, 0.f, 0.f);
    if (t == 0) Kcnt = 0;

    // bitonic sort ascending on ~K (= score desc, index asc)
    for (unsigned k = 2; k <= 2048; k <<= 1) {
        for (unsigned j = k >> 1; j > 0; j >>= 1) {
            __syncthreads();
            for (unsigned i = t; i < 2048; i += 1024) {
                unsigned p = i ^ j;
                if (p > i) {
                    bool up = ((i & k) == 0);
                    unsigned long long a = skey[i], bq = skey[p];
                    if ((a > bq) == up) { skey[i] = bq; skey[p] = a; }
                }
            }
        }
    }
    __syncthreads();

    float* keepout = out + 6 * BATCH * NP + b * NP;
    for (int base = 0; base < NP; base += 64) {
        unsigned long long ik = skey[base + l];
        bool valid = (ik != ~0ull);
        unsigned long long vm = __ballot(valid);
        if (vm == 0) break;

        unsigned idx = 0;
        float4 bx = make_float4(0.f, 0.f, 0.f, 0.f);
        float ar = 0.f;
        if (valid) {
            unsigned long long K = ~ik;
            idx = 0xFFFFFFFFu - (unsigned)(K & 0xFFFFFFFFull);
            bx  = CBox[idx];
            ar  = (bx.z - bx.x) * (bx.w - bx.y);
        }
        int prevK = Kcnt;
        int prevKpad = (prevK + 63) & ~63;

        // test vs previously-kept: wave w handles kept indices w*4+0..3 (+64n)
        bool sup = false;
        for (int kk = w * 4; kk < prevKpad; kk += 64) {
            float4 kb0 = KBox[kk],     kb1 = KBox[kk + 1];
            float4 kb2 = KBox[kk + 2], kb3 = KBox[kk + 3];
#pragma unroll
            for (int q = 0; q < 4; ++q) {
                float4 kb = q == 0 ? kb0 : q == 1 ? kb1 : q == 2 ? kb2 : kb3;
                float kar = (kb.z - kb.x) * (kb.w - kb.y);
                float xx1 = fmaxf(kb.x, bx.x);
                float yy1 = fmaxf(kb.y, bx.y);
                float xx2 = fminf(kb.z, bx.z);
                float yy2 = fminf(kb.w, bx.w);
                float ww = fmaxf(1e-28f, xx2 - xx1);
                float hh = fmaxf(1e-28f, yy2 - yy1);
                float inter = ww * hh;
                float iou = inter / (kar + ar - inter + 1e-14f);
                sup |= (iou > NMS_THR);
            }
        }
        wmask[w] = __ballot(valid && !sup);
        __syncthreads();

        if (w == 0) {
            unsigned long long alive = wmask[0];
#pragma unroll
            for (int q = 1; q < 16; ++q) alive &= wmask[q];
            // per-lane suppressor mask via shfl broadcasts (no LDS)
            unsigned long long smask = 0;
            for (int s = 0; s < 63; ++s) {
                float ox1 = __shfl(bx.x, s), oy1 = __shfl(bx.y, s);
                float ox2 = __shfl(bx.z, s), oy2 = __shfl(bx.w, s);
                float oar = (ox2 - ox1) * (oy2 - oy1);
                float xx1 = fmaxf(ox1, bx.x);
                float yy1 = fmaxf(oy1, bx.y);
                float xx2 = fminf(ox2, bx.z);
                float yy2 = fminf(oy2, bx.w);
                float ww = fmaxf(1e-28f, xx2 - xx1);
                float hh = fmaxf(1e-28f, yy2 - yy1);
                float inter = ww * hh;
                float iou = inter / (oar + ar - inter + 1e-14f);
                if (s < l && iou > NMS_THR) smask |= (1ull << s);
            }
            unsigned long long kept = 0;
            while (alive) {
                int s = __builtin_ctzll(alive);        // best remaining score
                kept |= (1ull << s);
                alive &= ~(1ull << s);
                unsigned long long dead = __ballot((smask >> s) & 1ull);
                alive &= ~dead;
            }
            if ((kept >> l) & 1ull) {
                int pos = prevK + __builtin_popcountll(kept & ((1ull << l) - 1ull));
                KBox[pos] = bx;
                keepout[idx] = 1.0f;
            }
            if (l == 0) Kcnt = prevK + __builtin_popcountll(kept);
        }
        __syncthreads();
    }
}

// ---------------------------------------------------------------------------
extern "C" void kernel_launch(void* const* d_in, const int* in_sizes, int n_in,
                              void* d_out, int out_size, void* d_ws, size_t ws_size,
                              hipStream_t stream) {
    const float* x      = (const float*)d_in[0];
    const float* cls_w  = (const float*)d_in[1];
    const float* cls_b  = (const float*)d_in[2];
    const float* reg_w  = (const float*)d_in[3];
    const float* reg_b  = (const float*)d_in[4];
    const float* obj_w  = (const float*)d_in[5];
    const float* obj_b  = (const float*)d_in[6];
    const float* clsp_w = (const float*)d_in[7];
    const float* clsp_b = (const float*)d_in[8];
    const float* regp_w = (const float*)d_in[9];
    const float* regp_b = (const float*)d_in[10];
    float* out = (float*)d_out;

    _Float16* ws = (_Float16*)d_ws;
    _Float16* Xh = ws;
    _Float16* Xl = ws + FPLANE;
    _Float16* Ah = ws + 2 * FPLANE;
    _Float16* Al = ws + 3 * FPLANE;
    _Float16* Bh = ws + 4 * FPLANE;
    _Float16* Bl = ws + 5 * FPLANE;
    _Float16* Wh = ws + 6 * FPLANE;
    _Float16* Wl = Wh + WSZ;
    const size_t LW = (size_t)CH * CH * 9;

    border_zero<<<dim3(1968), 256, 0, stream>>>((uint4*)d_ws);
    xprep_kernel<<<dim3(25, 8, 8), 256, 0, stream>>>(x, Xh, Xl);

    dim3 wgrid(16, 16), cgrid(200, 2), blk(256);

    // cls chain: xp -> A -> B (cf = B)
    wtrans_kernel<<<wgrid, blk, 0, stream>>>(cls_w, Wh, Wl);
    conv_mfma<<<cgrid, blk, 0, stream>>>(Xh, Xl, Wh, Wl, cls_b,          Ah, Al);
    wtrans_kernel<<<wgrid, blk, 0, stream>>>(cls_w + LW, Wh, Wl);
    conv_mfma<<<cgrid, blk, 0, stream>>>(Ah, Al, Wh, Wl, cls_b + CH,     Bh, Bl);
    // reg chain: xp -> A -> xp -> A -> xp (rf = xp)
    wtrans_kernel<<<wgrid, blk, 0, stream>>>(reg_w, Wh, Wl);
    conv_mfma<<<cgrid, blk, 0, stream>>>(Xh, Xl, Wh, Wl, reg_b,          Ah, Al);
    wtrans_kernel<<<wgrid, blk, 0, stream>>>(reg_w + LW, Wh, Wl);
    conv_mfma<<<cgrid, blk, 0, stream>>>(Ah, Al, Wh, Wl, reg_b + CH,     Xh, Xl);
    wtrans_kernel<<<wgrid, blk, 0, stream>>>(reg_w + 2 * LW, Wh, Wl);
    conv_mfma<<<cgrid, blk, 0, stream>>>(Xh, Xl, Wh, Wl, reg_b + 2 * CH, Ah, Al);
    wtrans_kernel<<<wgrid, blk, 0, stream>>>(reg_w + 3 * LW, Wh, Wl);
    conv_mfma<<<cgrid, blk, 0, stream>>>(Ah, Al, Wh, Wl, reg_b + 3 * CH, Xh, Xl);

    head_kernel<<<dim3(3200), 256, 0, stream>>>(Xh, Xl, Bh, Bl, obj_w, obj_b,
                                                clsp_w, clsp_b, regp_w, regp_b, out);
    nms_kernel<<<dim3(NCLS, BATCH), 1024, 0, stream>>>(out);
}